// Round 14
// baseline (425.979 us; speedup 1.0000x reference)
//
#include <hip/hip_runtime.h>
#include <hip/hip_bf16.h>

#define GN 20000          // nodes
#define GE 320000         // edges (without self loops)
#define GETOT (GE + GN)   // edges + self loops
#define GH 4              // heads
#define NROW 20096        // padded row count (staging over-read safety, 157*128)

typedef __attribute__((ext_vector_type(8))) _Float16 f16x8;  // 8 fp16 = 4 VGPR
typedef __attribute__((ext_vector_type(4))) float f32x4;

// ---------------------------------------------------------------------------
// edge_index dtype detection (int64 vs x64-disabled int32)
// ---------------------------------------------------------------------------
__global__ void detect_dtype_kernel(const void* __restrict__ ei, int* __restrict__ flag) {
    if (threadIdx.x == 0 && blockIdx.x == 0) {
        const long long* p = (const long long*)ei;
        int ok = 1;
        for (int i = 0; i < 16; ++i) {
            long long v = p[i];
            if (v < 0 || v >= GN) ok = 0;
        }
        *flag = ok;
    }
}

__device__ __forceinline__ int load_idx(const void* ei, int is64, long long pos) {
    if (is64) return (int)((const long long*)ei)[pos];
    return ((const int*)ei)[pos];
}

// ---------------------------------------------------------------------------
// CSR build
// ---------------------------------------------------------------------------
__global__ void hist_kernel(const void* __restrict__ ei, const int* __restrict__ flagp,
                            int* __restrict__ counts) {
    int e = blockIdx.x * blockDim.x + threadIdx.x;
    if (e >= GETOT) return;
    int d;
    if (e < GE) d = load_idx(ei, *flagp, (long long)GE + e);
    else        d = e - GE;
    atomicAdd(&counts[d], 1);
}

// 20000-element exclusive scan: 20 serial elems/thread + ONE 1024-wide scan.
__global__ __launch_bounds__(1024) void scan_kernel(const int* __restrict__ counts,
                                                    int* __restrict__ offsets,
                                                    int* __restrict__ cursor) {
    __shared__ int sh[1024];
    const int tid = threadIdx.x;
    constexpr int CH = 20;                 // 1024*20 = 20480 >= GN
    const int base = tid * CH;
    int loc[CH];
    int sum = 0;
#pragma unroll
    for (int i = 0; i < CH; ++i) {
        int idx = base + i;
        int v = (idx < GN) ? counts[idx] : 0;
        loc[i] = sum;                      // exclusive prefix within chunk
        sum += v;
    }
    sh[tid] = sum;
    __syncthreads();
    for (int o = 1; o < 1024; o <<= 1) {   // 10 steps, 20 barriers total
        int t = (tid >= o) ? sh[tid - o] : 0;
        __syncthreads();
        sh[tid] += t;
        __syncthreads();
    }
    const int excl = tid ? sh[tid - 1] : 0;
#pragma unroll
    for (int i = 0; i < CH; ++i) {
        int idx = base + i;
        if (idx < GN) {
            int o = excl + loc[i];
            offsets[idx] = o;
            cursor[idx]  = o;
        }
    }
    if (tid == 1023) offsets[GN] = sh[1023];
}

__global__ void scatter_kernel(const void* __restrict__ ei, const int* __restrict__ flagp,
                               int* __restrict__ cursor, int* __restrict__ csr_src) {
    int e = blockIdx.x * blockDim.x + threadIdx.x;
    if (e >= GETOT) return;
    int s, d;
    if (e < GE) {
        int is64 = *flagp;
        s = load_idx(ei, is64, e);
        d = load_idx(ei, is64, (long long)GE + e);
    } else {
        s = d = e - GE;
    }
    int pos = atomicAdd(&cursor[d], 1);
    csr_src[pos] = s;
}

// ---------------------------------------------------------------------------
// fp16 helpers
// ---------------------------------------------------------------------------
__device__ __forceinline__ float h2f(unsigned u) {
    unsigned short us = (unsigned short)u;
    _Float16 h;
    __builtin_memcpy(&h, &us, 2);
    return (float)h;
}
__device__ __forceinline__ unsigned short f2h_bits(float v) {
    _Float16 h = (_Float16)v;
    unsigned short us;
    __builtin_memcpy(&us, &h, 2);
    return us;
}

// W fp32 [K][N] -> Wt fp16 [N][Kpad] (transposed, zero-padded K)
__global__ void convert_wt(const float* __restrict__ W,
                           _Float16* __restrict__ thi,
                           int K, int N, int Kpad) {
    __shared__ float tile[32][33];
    int kb = blockIdx.x * 32, nb = blockIdx.y * 32;
    for (int i = threadIdx.y; i < 32; i += 8) {
        int k = kb + i, n = nb + threadIdx.x;
        tile[i][threadIdx.x] = (k < K) ? W[(size_t)k * N + n] : 0.f;
    }
    __syncthreads();
    for (int i = threadIdx.y; i < 32; i += 8) {
        int n = nb + i, k = kb + threadIdx.x;
        thi[(size_t)n * Kpad + k] = (_Float16)tile[threadIdx.x][i];
    }
}

// ---------------------------------------------------------------------------
// LDS swizzles.
// 16-bit tiles (64B rows): phys = a ^ (((a>>6)&7)<<4)   [proven r2-r13]
// fp32 tiles (128B rows):  phys = a ^ (((a>>7)&7)<<4)   (involution, r5-r13)
// ---------------------------------------------------------------------------
__device__ __forceinline__ int swz(int a) { return a ^ (((a >> 6) & 7) << 4); }
__device__ __forceinline__ int invswz(int p) {
    int b8 = (p >> 8) & 1, b7 = (p >> 7) & 1;
    int a6 = ((p >> 6) & 1) ^ b8;
    int a5 = ((p >> 5) & 1) ^ b7;
    int a4 = ((p >> 4) & 1) ^ a6;
    return (p & ~0x70) | (a4 << 4) | (a5 << 5) | (a6 << 6);
}
__device__ __forceinline__ int swzA32(int a) { return a ^ (((a >> 7) & 7) << 4); }

#define GLDS16(gsrc, ldst) __builtin_amdgcn_global_load_lds( \
    (const __attribute__((address_space(1))) void*)(gsrc),   \
    (__attribute__((address_space(3))) void*)(ldst), 16, 0, 0)

// ---------------------------------------------------------------------------
// Layer-0 GEMM (r14): C[fp16] = x_fp32 @ W_fp16, BM=128, BN=256, BK=32.
// 512 threads, 8 waves (2x4), wave tile 64x64, mfma_f32_16x16x32_f16.
// Rationale: GEMM is bound by logical staged bytes through L2/L3 (~7.2 TB/s
// effective; r13 post-mortem). BN=256 halves A re-staging: 972 -> 648 MB.
// LDS/buffer = 32KB [A32 16K | W 16K], dbuf 64KB -> 2 blocks/CU.
// 4-load STAGE -> vmcnt(4); A fp32 direct, cvt hidden via split lgkm wait.
// ---------------------------------------------------------------------------
__global__ __launch_bounds__(512) void gemm_f16_l0(
        const float* __restrict__ A32, int lda, int K,
        const _Float16* __restrict__ Whi,
        int Kpad, _Float16* __restrict__ Cp, int M, int N, int NC) {
    __shared__ char lds[65536];
    const int tid = threadIdx.x;

    // bijective XCD-chunked remap (m204), row-major work order
    const int nwg = gridDim.x;
    const int q = nwg >> 3, r = nwg & 7;
    const int xcd = blockIdx.x & 7, sub = blockIdx.x >> 3;
    const int orig = (xcd < r ? xcd * (q + 1) : r * (q + 1) + (xcd - r) * q) + sub;
    const int brow = (orig / NC) * 128;
    const int bcol = (orig % NC) * 256;

    const int lane = tid & 63, wid = tid >> 6;
    const int wr = wid >> 2, wc = wid & 3;          // 2x4 wave grid
    const int l4 = lane & 15, kg = lane >> 4;

    // A staging map: 128x32 fp32 = 16KB = 2 passes x 512x16B
    int rA[2], eA[2];
#pragma unroll
    for (int p = 0; p < 2; ++p) {
        int a = swzA32(p * 8192 + tid * 16);
        int rr = brow + (a >> 7);                   // row 0..127
        rA[p] = rr < M ? rr : M - 1;                // clamp; masked at C store
        eA[p] = (a & 127) >> 2;                     // fp32 elem offset
    }
    // W staging map: 256x32 fp16 = 16KB = 2 passes x 512x16B
    int rB[2], eB[2];
#pragma unroll
    for (int p = 0; p < 2; ++p) {
        int a = invswz(p * 8192 + tid * 16);
        rB[p] = bcol + (a >> 6);                    // row 0..255; N%256==0 -> valid
        eB[p] = (a & 63) >> 1;
    }

    auto STAGE = [&](int buf, int k0) {             // exactly 4 global_load_lds
        char* bb = lds + buf * 32768;
#pragma unroll
        for (int p = 0; p < 2; ++p) {
            int kk = k0 + eA[p];
            if (kk >= K) kk = 0;                    // tail cols hit W zero-pad
            GLDS16(A32 + (size_t)rA[p] * lda + kk, bb + p * 8192 + tid * 16);
        }
#pragma unroll
        for (int p = 0; p < 2; ++p)
            GLDS16(Whi + (size_t)rB[p] * Kpad + k0 + eB[p], bb + 16384 + p * 8192 + tid * 16);
    };

    // fragment read offsets
    int aoff[4], boff[4];
#pragma unroll
    for (int m = 0; m < 4; ++m) {
        aoff[m] = swzA32((wr * 64 + m * 16 + l4) * 128 + kg * 32);
        boff[m] = swz((wc * 64 + m * 16 + l4) * 64 + kg * 16);
    }

    f32x4 acc[4][4];
#pragma unroll
    for (int m = 0; m < 4; ++m)
#pragma unroll
        for (int n = 0; n < 4; ++n) acc[m][n] = (f32x4)(0.f);

    const int nk = Kpad / 32;
    STAGE(0, 0);

    for (int t = 0; t < nk; ++t) {
        if (t + 1 < nk) {
            STAGE((t + 1) & 1, (t + 1) * 32);                // prefetch in flight
            asm volatile("s_waitcnt vmcnt(4)" ::: "memory"); // wait this tile only
        } else {
            asm volatile("s_waitcnt vmcnt(0)" ::: "memory"); // tail drain
        }
        __builtin_amdgcn_s_barrier();
        __builtin_amdgcn_sched_barrier(0);

        char* bb = lds + (t & 1) * 32768;
        f16x8 av[4], wh[4];
        f32x4 u0[4], u1[4];
#pragma unroll
        for (int m = 0; m < 4; ++m) {                // 8 ds_read_b128 (A)
            u0[m] = *(const f32x4*)(bb + aoff[m]);
            u1[m] = *(const f32x4*)(bb + (aoff[m] ^ 16));
        }
        __builtin_amdgcn_sched_barrier(0);
#pragma unroll
        for (int n = 0; n < 4; ++n)                  // 4 ds_read_b128 (W)
            wh[n] = *(const f16x8*)(bb + 16384 + boff[n]);
        __builtin_amdgcn_sched_barrier(0);
        asm volatile("s_waitcnt lgkmcnt(4)" ::: "memory");   // A complete
        __builtin_amdgcn_sched_barrier(0);
#pragma unroll
        for (int m = 0; m < 4; ++m) {                // cvt overlaps W drain
            av[m][0] = (_Float16)u0[m].x; av[m][1] = (_Float16)u0[m].y;
            av[m][2] = (_Float16)u0[m].z; av[m][3] = (_Float16)u0[m].w;
            av[m][4] = (_Float16)u1[m].x; av[m][5] = (_Float16)u1[m].y;
            av[m][6] = (_Float16)u1[m].z; av[m][7] = (_Float16)u1[m].w;
        }
        asm volatile("s_waitcnt lgkmcnt(0)" ::: "memory");
        __builtin_amdgcn_sched_barrier(0);

#pragma unroll
        for (int m = 0; m < 4; ++m)
#pragma unroll
            for (int n = 0; n < 4; ++n)
                acc[m][n] = __builtin_amdgcn_mfma_f32_16x16x32_f16(av[m], wh[n], acc[m][n], 0, 0, 0);
        __builtin_amdgcn_s_barrier();
    }

    // epilogue: D col = lane&15, row = (lane>>4)*4 + r
#pragma unroll
    for (int m = 0; m < 4; ++m) {
        int gr0 = brow + wr * 64 + m * 16 + (lane >> 4) * 4;
#pragma unroll
        for (int n = 0; n < 4; ++n) {
            int gc = bcol + wc * 64 + n * 16 + l4;
#pragma unroll
            for (int rr2 = 0; rr2 < 4; ++rr2) {
                int gr = gr0 + rr2;
                if (gr < M) Cp[(size_t)gr * N + gc] = (_Float16)acc[m][n][rr2];
            }
        }
    }
}

// ---------------------------------------------------------------------------
// fp16 1-pass MFMA GEMM (layers 1-3):  C = A_fp16 @ W_fp16 (fp32 accumulate)
// BM=128, BN=128, BK=32, 4 waves (2x2), wave tile 64x64.
// MODE 0: C fp16.  MODE 2: C fp32 (layer 3).
// LDS 16K/buf [A 8K | W 8K], dbuf 32K -> 4 blocks/CU. vmcnt(4) counted waits.
// ---------------------------------------------------------------------------
template <int MODE>
__global__ __launch_bounds__(256, 4) void gemm_f16(
        const _Float16* __restrict__ Af, int lda,
        const _Float16* __restrict__ Whi,
        int Kpad, void* __restrict__ Cp, int M, int N, int NC) {
    __shared__ char lds[32768];
    const int tid = threadIdx.x;

    const int nwg = gridDim.x;
    const int q = nwg >> 3, r = nwg & 7;
    const int xcd = blockIdx.x & 7, sub = blockIdx.x >> 3;
    const int orig = (xcd < r ? xcd * (q + 1) : r * (q + 1) + (xcd - r) * q) + sub;
    const int brow = (orig / NC) * 128;
    const int bcol = (orig % NC) * 128;

    const int lane = tid & 63, wid = tid >> 6;
    const int wr = wid >> 1, wc = wid & 1;
    const int l4 = lane & 15, kg = lane >> 4;

    int row8[2], ecol[2];
#pragma unroll
    for (int p = 0; p < 2; ++p) {
        int a = invswz(p * 4096 + tid * 16);
        row8[p] = a >> 6;
        ecol[p] = (a & 63) >> 1;
    }
    int rA[2], rB[2];
#pragma unroll
    for (int p = 0; p < 2; ++p) {
        rA[p] = brow + row8[p];           // < NROW (buffers over-allocated)
        rB[p] = bcol + row8[p];           // N % 128 == 0 -> valid
    }

    auto STAGE = [&](int buf, int k0) {   // exactly 4 global_load_lds
        char* bb = lds + buf * 16384;
#pragma unroll
        for (int p = 0; p < 2; ++p) {
            GLDS16(Af  + (size_t)rA[p] * lda  + k0 + ecol[p], bb + p * 4096 + tid * 16);
            GLDS16(Whi + (size_t)rB[p] * Kpad + k0 + ecol[p], bb + 8192 + p * 4096 + tid * 16);
        }
    };

    int aoff[4], boff[4];
#pragma unroll
    for (int m = 0; m < 4; ++m) {
        aoff[m] = swz((wr * 64 + m * 16 + l4) * 64 + kg * 16);
        boff[m] = swz((wc * 64 + m * 16 + l4) * 64 + kg * 16);
    }

    f32x4 acc[4][4];
#pragma unroll
    for (int m = 0; m < 4; ++m)
#pragma unroll
        for (int n = 0; n < 4; ++n) acc[m][n] = (f32x4)(0.f);

    const int nk = Kpad / 32;
    STAGE(0, 0);

    for (int t = 0; t < nk; ++t) {
        if (t + 1 < nk) {
            STAGE((t + 1) & 1, (t + 1) * 32);
            asm volatile("s_waitcnt vmcnt(4)" ::: "memory");
        } else {
            asm volatile("s_waitcnt vmcnt(0)" ::: "memory");
        }
        __builtin_amdgcn_s_barrier();
        __builtin_amdgcn_sched_barrier(0);

        char* bb = lds + (t & 1) * 16384;
        f16x8 av[4], wh[4];
#pragma unroll
        for (int m = 0; m < 4; ++m) av[m] = *(const f16x8*)(bb + aoff[m]);
#pragma unroll
        for (int n = 0; n < 4; ++n) wh[n] = *(const f16x8*)(bb + 8192 + boff[n]);
        asm volatile("s_waitcnt lgkmcnt(0)" ::: "memory");
        __builtin_amdgcn_sched_barrier(0);

#pragma unroll
        for (int m = 0; m < 4; ++m)
#pragma unroll
            for (int n = 0; n < 4; ++n)
                acc[m][n] = __builtin_amdgcn_mfma_f32_16x16x32_f16(av[m], wh[n], acc[m][n], 0, 0, 0);
        __builtin_amdgcn_s_barrier();
    }

#pragma unroll
    for (int m = 0; m < 4; ++m) {
        int gr0 = brow + wr * 64 + m * 16 + (lane >> 4) * 4;
#pragma unroll
        for (int n = 0; n < 4; ++n) {
            int gc = bcol + wc * 64 + n * 16 + l4;
#pragma unroll
            for (int rr2 = 0; rr2 < 4; ++rr2) {
                int gr = gr0 + rr2;
                if (gr < M) {
                    size_t o = (size_t)gr * N + gc;
                    float v = acc[m][n][rr2];
                    if constexpr (MODE == 2) ((float*)Cp)[o] = v;
                    else                     ((_Float16*)Cp)[o] = (_Float16)v;
                }
            }
        }
    }
}

// ---------------------------------------------------------------------------
// a_s / a_d per-node logits (h in fp16 or fp32)
// ---------------------------------------------------------------------------
template <bool F16>
__global__ void att_sd_kernel(const void* __restrict__ hfeat,
                              const float* __restrict__ att_s,
                              const float* __restrict__ att_d,
                              float* __restrict__ a_s, float* __restrict__ a_d,
                              int C) {
    int wid  = (blockIdx.x * blockDim.x + threadIdx.x) >> 6;
    int lane = threadIdx.x & 63;
    if (wid >= GN) return;
#pragma unroll
    for (int h = 0; h < GH; ++h) {
        float ss = 0.f, sd = 0.f;
        for (int cc = lane; cc < C; cc += 64) {
            size_t idx = (size_t)wid * GH * C + h * C + cc;
            float v = F16 ? h2f(((const unsigned short*)hfeat)[idx])
                          : ((const float*)hfeat)[idx];
            ss += v * att_s[h * C + cc];
            sd += v * att_d[h * C + cc];
        }
#pragma unroll
        for (int o = 32; o; o >>= 1) {
            ss += __shfl_xor(ss, o);
            sd += __shfl_xor(sd, o);
        }
        if (lane == 0) { a_s[wid * GH + h] = ss; a_d[wid * GH + h] = sd; }
    }
}

// ---------------------------------------------------------------------------
// Softmax + aggregation, fp16 h input, CPT channels/thread (2 or 4).
// Output: fp16 activations (bias + ELU applied) = next GEMM's A operand.
// ---------------------------------------------------------------------------
template <int C, int CPT, int BLOCK>
__global__ __launch_bounds__(BLOCK) void gat_aggregate_f16(
        const unsigned short* __restrict__ hfeat,
        const float* __restrict__ a_s,
        const float* __restrict__ a_d,
        const int* __restrict__ offsets,
        const int* __restrict__ csr_src,
        const float* __restrict__ bias,
        unsigned short* __restrict__ of16) {
    constexpr int HC = GH * C;
    static_assert(BLOCK * CPT == HC, "coverage");
    const int n     = blockIdx.x;
    const int tid   = threadIdx.x;
    const int start = offsets[n];
    const int end   = offsets[n + 1];

    __shared__ float s_m[GH];
    __shared__ float s_den[GH];
    __shared__ int   s_src[64];
    __shared__ float s_al[GH][68];

    const float4 ad4 = *(const float4*)(a_d + n * GH);
    const float adh[GH] = {ad4.x, ad4.y, ad4.z, ad4.w};

    if (tid < 64) {
        float lmax[GH], lsum[GH];
#pragma unroll
        for (int h = 0; h < GH; ++h) lmax[h] = -1e30f;
        for (int e = start + tid; e < end; e += 64) {
            int s = csr_src[e];
            float4 as4 = *(const float4*)(a_s + s * GH);
            float l[GH] = {as4.x + adh[0], as4.y + adh[1], as4.z + adh[2], as4.w + adh[3]};
#pragma unroll
            for (int h = 0; h < GH; ++h) {
                float ll = l[h] > 0.f ? l[h] : 0.2f * l[h];
                lmax[h] = fmaxf(lmax[h], ll);
            }
        }
#pragma unroll
        for (int h = 0; h < GH; ++h)
#pragma unroll
            for (int o = 32; o; o >>= 1) lmax[h] = fmaxf(lmax[h], __shfl_xor(lmax[h], o));
#pragma unroll
        for (int h = 0; h < GH; ++h) lsum[h] = 0.f;
        for (int e = start + tid; e < end; e += 64) {
            int s = csr_src[e];
            float4 as4 = *(const float4*)(a_s + s * GH);
            float l[GH] = {as4.x + adh[0], as4.y + adh[1], as4.z + adh[2], as4.w + adh[3]};
#pragma unroll
            for (int h = 0; h < GH; ++h) {
                float ll = l[h] > 0.f ? l[h] : 0.2f * l[h];
                lsum[h] += __expf(ll - lmax[h]);
            }
        }
#pragma unroll
        for (int h = 0; h < GH; ++h)
#pragma unroll
            for (int o = 32; o; o >>= 1) lsum[h] += __shfl_xor(lsum[h], o);
        if (tid == 0) {
#pragma unroll
            for (int h = 0; h < GH; ++h) { s_m[h] = lmax[h]; s_den[h] = lsum[h]; }
        }
    }
    __syncthreads();

    float mm[GH], inv[GH];
#pragma unroll
    for (int h = 0; h < GH; ++h) { mm[h] = s_m[h]; inv[h] = 1.0f / s_den[h]; }

    const int ch0 = tid * CPT;
    const int hd  = ch0 / C;
    float acc[CPT];
#pragma unroll
    for (int j = 0; j < CPT; ++j) acc[j] = 0.f;

    for (int e0 = start; e0 < end; e0 += 64) {
        __syncthreads();
        if (tid < 64) {
            bool vld = (e0 + tid) < end;
            int s = vld ? csr_src[e0 + tid] : n;
            s_src[tid] = s;
            float4 as4 = *(const float4*)(a_s + s * GH);
            float l[GH] = {as4.x + adh[0], as4.y + adh[1], as4.z + adh[2], as4.w + adh[3]};
#pragma unroll
            for (int h = 0; h < GH; ++h) {
                float ll = l[h] > 0.f ? l[h] : 0.2f * l[h];
                s_al[h][tid] = vld ? __expf(ll - mm[h]) * inv[h] : 0.f;
            }
        }
        __syncthreads();
        int cnt = end - e0; if (cnt > 64) cnt = 64;
        int cnt4 = (cnt + 3) & ~3;
        for (int i = 0; i < cnt4; i += 4) {
            int4   ss = *(const int4*)&s_src[i];
            float4 aa = *(const float4*)&s_al[hd][i];
            if constexpr (CPT == 4) {
                uint2 v0 = ((const uint2*)(hfeat + (size_t)ss.x * HC))[tid];
                uint2 v1 = ((const uint2*)(hfeat + (size_t)ss.y * HC))[tid];
                uint2 v2 = ((const uint2*)(hfeat + (size_t)ss.z * HC))[tid];
                uint2 v3 = ((const uint2*)(hfeat + (size_t)ss.w * HC))[tid];
                acc[0] = fmaf(aa.x, h2f(v0.x & 0xffff), acc[0]);
                acc[1] = fmaf(aa.x, h2f(v0.x >> 16),    acc[1]);
                acc[2] = fmaf(aa.x, h2f(v0.y & 0xffff), acc[2]);
                acc[3] = fmaf(aa.x, h2f(v0.y >> 16),    acc[3]);
                acc[0] = fmaf(aa.y, h2f(v1.x & 0xffff), acc[0]);
                acc[1] = fmaf(aa.y, h2f(v1.x >> 16),    acc[1]);
                acc[2] = fmaf(aa.y, h2f(v1.y & 0xffff), acc[2]);
                acc[3] = fmaf(aa.y, h2f(v1.y >> 16),    acc[3]);
                acc[0] = fmaf(aa.z, h2f(v2.x & 0xffff), acc[0]);
                acc[1] = fmaf(aa.z, h2f(v2.x >> 16),    acc[1]);
                acc[2] = fmaf(aa.z, h2f(v2.y & 0xffff), acc[2]);
                acc[3] = fmaf(aa.z, h2f(v2.y >> 16),    acc[3]);
                acc[0] = fmaf(aa.w, h2f(v3.x & 0xffff), acc[0]);
                acc[1] = fmaf(aa.w, h2f(v3.x >> 16),    acc[1]);
                acc[2] = fmaf(aa.w, h2f(v3.y & 0xffff), acc[2]);
                acc[3] = fmaf(aa.w, h2f(v3.y >> 16),    acc[3]);
            } else {
                unsigned v0 = ((const unsigned*)(hfeat + (size_t)ss.x * HC))[tid];
                unsigned v1 = ((const unsigned*)(hfeat + (size_t)ss.y * HC))[tid];
                unsigned v2 = ((const unsigned*)(hfeat + (size_t)ss.z * HC))[tid];
                unsigned v3 = ((const unsigned*)(hfeat + (size_t)ss.w * HC))[tid];
                acc[0] = fmaf(aa.x, h2f(v0 & 0xffff), acc[0]);
                acc[1] = fmaf(aa.x, h2f(v0 >> 16),    acc[1]);
                acc[0] = fmaf(aa.y, h2f(v1 & 0xffff), acc[0]);
                acc[1] = fmaf(aa.y, h2f(v1 >> 16),    acc[1]);
                acc[0] = fmaf(aa.z, h2f(v2 & 0xffff), acc[0]);
                acc[1] = fmaf(aa.z, h2f(v2 >> 16),    acc[1]);
                acc[0] = fmaf(aa.w, h2f(v3 & 0xffff), acc[0]);
                acc[1] = fmaf(aa.w, h2f(v3 >> 16),    acc[1]);
            }
        }
    }

    // epilogue: bias + ELU -> fp16
    unsigned short hs[CPT];
#pragma unroll
    for (int j = 0; j < CPT; ++j) {
        float v = acc[j] + bias[ch0 + j];
        v = v > 0.f ? v : expm1f(v);
        hs[j] = f2h_bits(v);
    }
    unsigned short* op = of16 + (size_t)n * HC + ch0;
    if constexpr (CPT == 4) {
        uint2 hw = make_uint2((unsigned)hs[0] | ((unsigned)hs[1] << 16),
                              (unsigned)hs[2] | ((unsigned)hs[3] << 16));
        *(uint2*)op = hw;
    } else {
        *(unsigned*)op = (unsigned)hs[0] | ((unsigned)hs[1] << 16);
    }
}

// ---------------------------------------------------------------------------
// Final layer aggregation: fp32 h input, head-mean + bias -> fp32 d_out.
// ---------------------------------------------------------------------------
__global__ __launch_bounds__(128) void gat_aggregate_final(
        const float* __restrict__ hfeat,
        const float* __restrict__ a_s,
        const float* __restrict__ a_d,
        const int* __restrict__ offsets,
        const int* __restrict__ csr_src,
        const float* __restrict__ bias,
        float* __restrict__ outf) {
    constexpr int C = 64, HC = GH * C;
    const int n     = blockIdx.x;
    const int tid   = threadIdx.x;
    const int start = offsets[n];
    const int end   = offsets[n + 1];

    __shared__ float s_m[GH];
    __shared__ float s_den[GH];
    __shared__ int   s_src[64];
    __shared__ float s_al[GH][68];
    __shared__ float sacc[256];

    const float4 ad4 = *(const float4*)(a_d + n * GH);
    const float adh[GH] = {ad4.x, ad4.y, ad4.z, ad4.w};

    if (tid < 64) {
        float lmax[GH], lsum[GH];
#pragma unroll
        for (int h = 0; h < GH; ++h) lmax[h] = -1e30f;
        for (int e = start + tid; e < end; e += 64) {
            int s = csr_src[e];
            float4 as4 = *(const float4*)(a_s + s * GH);
            float l[GH] = {as4.x + adh[0], as4.y + adh[1], as4.z + adh[2], as4.w + adh[3]};
#pragma unroll
            for (int h = 0; h < GH; ++h) {
                float ll = l[h] > 0.f ? l[h] : 0.2f * l[h];
                lmax[h] = fmaxf(lmax[h], ll);
            }
        }
#pragma unroll
        for (int h = 0; h < GH; ++h)
#pragma unroll
            for (int o = 32; o; o >>= 1) lmax[h] = fmaxf(lmax[h], __shfl_xor(lmax[h], o));
#pragma unroll
        for (int h = 0; h < GH; ++h) lsum[h] = 0.f;
        for (int e = start + tid; e < end; e += 64) {
            int s = csr_src[e];
            float4 as4 = *(const float4*)(a_s + s * GH);
            float l[GH] = {as4.x + adh[0], as4.y + adh[1], as4.z + adh[2], as4.w + adh[3]};
#pragma unroll
            for (int h = 0; h < GH; ++h) {
                float ll = l[h] > 0.f ? l[h] : 0.2f * l[h];
                lsum[h] += __expf(ll - lmax[h]);
            }
        }
#pragma unroll
        for (int h = 0; h < GH; ++h)
#pragma unroll
            for (int o = 32; o; o >>= 1) lsum[h] += __shfl_xor(lsum[h], o);
        if (tid == 0) {
#pragma unroll
            for (int h = 0; h < GH; ++h) { s_m[h] = lmax[h]; s_den[h] = lsum[h]; }
        }
    }
    __syncthreads();

    float mm[GH], inv[GH];
#pragma unroll
    for (int h = 0; h < GH; ++h) { mm[h] = s_m[h]; inv[h] = 1.0f / s_den[h]; }

    const int hd = (2 * tid) / C;
    float2 acc = make_float2(0.f, 0.f);

    for (int e0 = start; e0 < end; e0 += 64) {
        __syncthreads();
        if (tid < 64) {
            bool vld = (e0 + tid) < end;
            int s = vld ? csr_src[e0 + tid] : n;
            s_src[tid] = s;
            float4 as4 = *(const float4*)(a_s + s * GH);
            float l[GH] = {as4.x + adh[0], as4.y + adh[1], as4.z + adh[2], as4.w + adh[3]};
#pragma unroll
            for (int h = 0; h < GH; ++h) {
                float ll = l[h] > 0.f ? l[h] : 0.2f * l[h];
                s_al[h][tid] = vld ? __expf(ll - mm[h]) * inv[h] : 0.f;
            }
        }
        __syncthreads();
        int cnt = end - e0; if (cnt > 64) cnt = 64;
        int cnt4 = (cnt + 3) & ~3;
        for (int i = 0; i < cnt4; i += 4) {
            int4   ss = *(const int4*)&s_src[i];
            float4 aa = *(const float4*)&s_al[hd][i];
            float2 v0 = ((const float2*)(hfeat + (size_t)ss.x * HC))[tid];
            float2 v1 = ((const float2*)(hfeat + (size_t)ss.y * HC))[tid];
            float2 v2 = ((const float2*)(hfeat + (size_t)ss.z * HC))[tid];
            float2 v3 = ((const float2*)(hfeat + (size_t)ss.w * HC))[tid];
            acc.x = fmaf(aa.x, v0.x, acc.x); acc.y = fmaf(aa.x, v0.y, acc.y);
            acc.x = fmaf(aa.y, v1.x, acc.x); acc.y = fmaf(aa.y, v1.y, acc.y);
            acc.x = fmaf(aa.z, v2.x, acc.x); acc.y = fmaf(aa.z, v2.y, acc.y);
            acc.x = fmaf(aa.w, v3.x, acc.x); acc.y = fmaf(aa.w, v3.y, acc.y);
        }
    }

    sacc[2 * tid]     = acc.x;
    sacc[2 * tid + 1] = acc.y;
    __syncthreads();
    if (tid < C) {
        float v = 0.f;
#pragma unroll
        for (int h = 0; h < GH; ++h) v += sacc[h * C + tid];
        outf[(size_t)n * C + tid] = v * (1.0f / GH) + bias[tid];
    }
}

// ---------------------------------------------------------------------------
extern "C" void kernel_launch(void* const* d_in, const int* in_sizes, int n_in,
                              void* d_out, int out_size, void* d_ws, size_t ws_size,
                              hipStream_t stream) {
    const float* x  = (const float*)d_in[0];
    const void*  ei = d_in[1];
    const float* W[4]  = {(const float*)d_in[2],  (const float*)d_in[6],
                          (const float*)d_in[10], (const float*)d_in[14]};
    const float* AS[4] = {(const float*)d_in[3],  (const float*)d_in[7],
                          (const float*)d_in[11], (const float*)d_in[15]};
    const float* AD[4] = {(const float*)d_in[4],  (const float*)d_in[8],
                          (const float*)d_in[12], (const float*)d_in[16]};
    const float* BI[4] = {(const float*)d_in[5],  (const float*)d_in[9],
                          (const float*)d_in[13], (const float*)d_in[17]};

    char*  w   = (char*)d_ws;
    size_t off = 0;
    auto alloc = [&](size_t b) -> char* {
        char* p = w + off;
        off += (b + 255) & ~(size_t)255;
        return p;
    };
    int*   flag    = (int*)alloc(4);
    int*   counts  = (int*)alloc((GN + 1) * sizeof(int));
    int*   offsets = (int*)alloc((GN + 1) * sizeof(int));
    int*   cursor  = (int*)alloc(GN * sizeof(int));
    int*   csr_src = (int*)alloc((size_t)GETOT * sizeof(int));
    float* a_s     = (float*)alloc((size_t)GN * GH * sizeof(float));
    float* a_d     = (float*)alloc((size_t)GN * GH * sizeof(float));
    unsigned short* hA = (unsigned short*)alloc((size_t)NROW * 512 * 2);   // GEMM out h (fp16)
    unsigned short* hB = (unsigned short*)alloc((size_t)NROW * 512 * 2);   // agg out act (fp16)
    float* hbuf    = (float*)alloc((size_t)NROW * 256 * sizeof(float));    // L3 fp32 h
    _Float16* wt   = (_Float16*)alloc((size_t)512 * 2016 * 2);             // 2.06 MB
    (void)in_sizes; (void)n_in; (void)out_size; (void)ws_size;

    // ---- CSR by destination (layer-invariant) ----
    detect_dtype_kernel<<<1, 64, 0, stream>>>(ei, flag);
    hipMemsetAsync(counts, 0, (GN + 1) * sizeof(int), stream);
    int eblocks = (GETOT + 255) / 256;
    hist_kernel<<<eblocks, 256, 0, stream>>>(ei, flag, counts);
    scan_kernel<<<1, 1024, 0, stream>>>(counts, offsets, cursor);
    scatter_kernel<<<eblocks, 256, 0, stream>>>(ei, flag, cursor, csr_src);

    const dim3 tb(32, 8);
    const int NR = (GN + 127) / 128;   // 157 row blocks

    // ---- layer 0: 2000 -> 4x128 concat, ELU (BN=256, fp32 x direct) ----
    convert_wt<<<dim3(2016 / 32, 512 / 32), tb, 0, stream>>>(W[0], wt, 2000, 512, 2016);
    gemm_f16_l0<<<NR * 2, 512, 0, stream>>>(x, 2000, 2000, wt, 2016,
                                            (_Float16*)hA, GN, 512, 2);
    att_sd_kernel<true><<<(GN * 64) / 256, 256, 0, stream>>>(hA, AS[0], AD[0], a_s, a_d, 128);
    gat_aggregate_f16<128, 4, 128><<<GN, 128, 0, stream>>>(hA, a_s, a_d, offsets, csr_src,
                                                           BI[0], hB);
    // ---- layer 1: 512 -> 4x64 concat, ELU ----
    convert_wt<<<dim3(512 / 32, 256 / 32), tb, 0, stream>>>(W[1], wt, 512, 256, 512);
    gemm_f16<0><<<NR * 2, 256, 0, stream>>>((_Float16*)hB, 512, wt, 512, hA, GN, 256, 2);
    att_sd_kernel<true><<<(GN * 64) / 256, 256, 0, stream>>>(hA, AS[1], AD[1], a_s, a_d, 64);
    gat_aggregate_f16<64, 4, 64><<<GN, 64, 0, stream>>>(hA, a_s, a_d, offsets, csr_src,
                                                        BI[1], hB);
    // ---- layer 2: 256 -> 4x32 concat, ELU ----
    convert_wt<<<dim3(256 / 32, 128 / 32), tb, 0, stream>>>(W[2], wt, 256, 128, 256);
    gemm_f16<0><<<NR * 1, 256, 0, stream>>>((_Float16*)hB, 256, wt, 256, hA, GN, 128, 1);
    att_sd_kernel<true><<<(GN * 64) / 256, 256, 0, stream>>>(hA, AS[2], AD[2], a_s, a_d, 32);
    gat_aggregate_f16<32, 2, 64><<<GN, 64, 0, stream>>>(hA, a_s, a_d, offsets, csr_src,
                                                        BI[2], hB);
    // ---- layer 3: 128 -> 4x64 mean, no ELU (fp32 h for output fidelity) ----
    convert_wt<<<dim3(128 / 32, 256 / 32), tb, 0, stream>>>(W[3], wt, 128, 256, 128);
    gemm_f16<2><<<NR * 2, 256, 0, stream>>>((_Float16*)hB, 128, wt, 128, hbuf, GN, 256, 2);
    att_sd_kernel<false><<<(GN * 64) / 256, 256, 0, stream>>>(hbuf, AS[3], AD[3], a_s, a_d, 64);
    gat_aggregate_final<<<GN, 128, 0, stream>>>(hbuf, a_s, a_d, offsets, csr_src,
                                                BI[3], (float*)d_out);
}

// Round 15
// 398.347 us; speedup vs baseline: 1.0694x; 1.0694x over previous
//
#include <hip/hip_runtime.h>
#include <hip/hip_bf16.h>

#define GN 20000          // nodes
#define GE 320000         // edges (without self loops)
#define GETOT (GE + GN)   // edges + self loops
#define GH 4              // heads
#define NROW 20096        // padded row count (staging over-read safety, 157*128)

typedef __attribute__((ext_vector_type(8))) _Float16 f16x8;  // 8 fp16 = 4 VGPR
typedef __attribute__((ext_vector_type(4))) float f32x4;

// ---------------------------------------------------------------------------
// edge_index dtype detection (int64 vs x64-disabled int32)
// ---------------------------------------------------------------------------
__global__ void detect_dtype_kernel(const void* __restrict__ ei, int* __restrict__ flag) {
    if (threadIdx.x == 0 && blockIdx.x == 0) {
        const long long* p = (const long long*)ei;
        int ok = 1;
        for (int i = 0; i < 16; ++i) {
            long long v = p[i];
            if (v < 0 || v >= GN) ok = 0;
        }
        *flag = ok;
    }
}

__device__ __forceinline__ int load_idx(const void* ei, int is64, long long pos) {
    if (is64) return (int)((const long long*)ei)[pos];
    return ((const int*)ei)[pos];
}

// ---------------------------------------------------------------------------
// CSR build
// ---------------------------------------------------------------------------
__global__ void hist_kernel(const void* __restrict__ ei, const int* __restrict__ flagp,
                            int* __restrict__ counts) {
    int e = blockIdx.x * blockDim.x + threadIdx.x;
    if (e >= GETOT) return;
    int d;
    if (e < GE) d = load_idx(ei, *flagp, (long long)GE + e);
    else        d = e - GE;
    atomicAdd(&counts[d], 1);
}

// 20000-element exclusive scan: 20 serial elems/thread + ONE 1024-wide scan.
__global__ __launch_bounds__(1024) void scan_kernel(const int* __restrict__ counts,
                                                    int* __restrict__ offsets,
                                                    int* __restrict__ cursor) {
    __shared__ int sh[1024];
    const int tid = threadIdx.x;
    constexpr int CH = 20;                 // 1024*20 = 20480 >= GN
    const int base = tid * CH;
    int loc[CH];
    int sum = 0;
#pragma unroll
    for (int i = 0; i < CH; ++i) {
        int idx = base + i;
        int v = (idx < GN) ? counts[idx] : 0;
        loc[i] = sum;                      // exclusive prefix within chunk
        sum += v;
    }
    sh[tid] = sum;
    __syncthreads();
    for (int o = 1; o < 1024; o <<= 1) {   // 10 steps, 20 barriers total
        int t = (tid >= o) ? sh[tid - o] : 0;
        __syncthreads();
        sh[tid] += t;
        __syncthreads();
    }
    const int excl = tid ? sh[tid - 1] : 0;
#pragma unroll
    for (int i = 0; i < CH; ++i) {
        int idx = base + i;
        if (idx < GN) {
            int o = excl + loc[i];
            offsets[idx] = o;
            cursor[idx]  = o;
        }
    }
    if (tid == 1023) offsets[GN] = sh[1023];
}

__global__ void scatter_kernel(const void* __restrict__ ei, const int* __restrict__ flagp,
                               int* __restrict__ cursor, int* __restrict__ csr_src) {
    int e = blockIdx.x * blockDim.x + threadIdx.x;
    if (e >= GETOT) return;
    int s, d;
    if (e < GE) {
        int is64 = *flagp;
        s = load_idx(ei, is64, e);
        d = load_idx(ei, is64, (long long)GE + e);
    } else {
        s = d = e - GE;
    }
    int pos = atomicAdd(&cursor[d], 1);
    csr_src[pos] = s;
}

// ---------------------------------------------------------------------------
// fp16 helpers
// ---------------------------------------------------------------------------
__device__ __forceinline__ float h2f(unsigned u) {
    unsigned short us = (unsigned short)u;
    _Float16 h;
    __builtin_memcpy(&h, &us, 2);
    return (float)h;
}
__device__ __forceinline__ unsigned short f2h_bits(float v) {
    _Float16 h = (_Float16)v;
    unsigned short us;
    __builtin_memcpy(&us, &h, 2);
    return us;
}

// W fp32 [K][N] -> Wt fp16 [N][Kpad] (transposed, zero-padded K)
__global__ void convert_wt(const float* __restrict__ W,
                           _Float16* __restrict__ thi,
                           int K, int N, int Kpad) {
    __shared__ float tile[32][33];
    int kb = blockIdx.x * 32, nb = blockIdx.y * 32;
    for (int i = threadIdx.y; i < 32; i += 8) {
        int k = kb + i, n = nb + threadIdx.x;
        tile[i][threadIdx.x] = (k < K) ? W[(size_t)k * N + n] : 0.f;
    }
    __syncthreads();
    for (int i = threadIdx.y; i < 32; i += 8) {
        int n = nb + i, k = kb + threadIdx.x;
        thi[(size_t)n * Kpad + k] = (_Float16)tile[threadIdx.x][i];
    }
}

// ---------------------------------------------------------------------------
// LDS swizzles.
// 16-bit tiles (64B rows): phys = a ^ (((a>>6)&7)<<4)   [proven r2-r14]
// fp32 tiles (128B rows):  phys = a ^ (((a>>7)&7)<<4)   (involution, r5-r14)
// ---------------------------------------------------------------------------
__device__ __forceinline__ int swz(int a) { return a ^ (((a >> 6) & 7) << 4); }
__device__ __forceinline__ int invswz(int p) {
    int b8 = (p >> 8) & 1, b7 = (p >> 7) & 1;
    int a6 = ((p >> 6) & 1) ^ b8;
    int a5 = ((p >> 5) & 1) ^ b7;
    int a4 = ((p >> 4) & 1) ^ a6;
    return (p & ~0x70) | (a4 << 4) | (a5 << 5) | (a6 << 6);
}
__device__ __forceinline__ int swzA32(int a) { return a ^ (((a >> 7) & 7) << 4); }

#define GLDS16(gsrc, ldst) __builtin_amdgcn_global_load_lds( \
    (const __attribute__((address_space(1))) void*)(gsrc),   \
    (__attribute__((address_space(3))) void*)(ldst), 16, 0, 0)

// ---------------------------------------------------------------------------
// fp16 1-pass MFMA GEMM with FUSED a_s/a_d epilogue (replaces att_sd pass).
// C = A @ W_fp16 (fp32 accumulate); BM=128, BN=128, BK=32, 4 waves (2x2).
// MODE 0: A fp16 (DMA), C fp16.    MODE 1: A fp32 direct (L0), C fp16.
// MODE 2: A fp16 (DMA), C fp32 (layer 3).
// CD = per-head channels of this layer's output (att vector length).
// Epilogue: partial dots v·att per row -> 16-lane shfl tree -> fp32 atomicAdd
// into a_s/a_d (pre-zeroed). Heads: cols n*16 grouped {0,1}/{2,3}; each
// 32-col group never straddles a head boundary (CD>=32, 64-aligned bases).
// ---------------------------------------------------------------------------
template <int MODE, int CD>
__global__ __launch_bounds__(256, MODE == 1 ? 3 : 4) void gemm_f16(
        const void* __restrict__ Ap, int lda, int K,
        const _Float16* __restrict__ Whi,
        int Kpad, void* __restrict__ Cp, int M, int N, int NC,
        const float* __restrict__ att_s, const float* __restrict__ att_d,
        float* __restrict__ a_s, float* __restrict__ a_d) {
    constexpr int BUFB = (MODE == 1) ? 24576 : 16384;
    constexpr int WOFF = (MODE == 1) ? 16384 : 8192;
    __shared__ char lds[2 * BUFB];
    const int tid = threadIdx.x;

    // bijective XCD-chunked remap (m204), row-major work order
    const int nwg = gridDim.x;
    const int q = nwg >> 3, r = nwg & 7;
    const int xcd = blockIdx.x & 7, sub = blockIdx.x >> 3;
    const int orig = (xcd < r ? xcd * (q + 1) : r * (q + 1) + (xcd - r) * q) + sub;
    const int brow = (orig / NC) * 128;
    const int bcol = (orig % NC) * 128;

    const int lane = tid & 63, wid = tid >> 6;
    const int wr = wid >> 1, wc = wid & 1;
    const int l4 = lane & 15, kg = lane >> 4;

    // W staging map (fp16 tile, 2 passes)
    int row8[2], ecol[2];
#pragma unroll
    for (int p = 0; p < 2; ++p) {
        int a = invswz(p * 4096 + tid * 16);
        row8[p] = a >> 6;
        ecol[p] = (a & 63) >> 1;
    }
    int rB[2];
#pragma unroll
    for (int p = 0; p < 2; ++p) rB[p] = bcol + row8[p];   // N % 128 == 0 -> valid

    // A staging map
    int rA2[2];                     // MODE 0/2 (fp16, 2 passes)
    int rA4[4], eA4[4];             // MODE 1   (fp32, 4 passes)
    if constexpr (MODE == 1) {
#pragma unroll
        for (int p = 0; p < 4; ++p) {
            int a = swzA32(p * 4096 + tid * 16);
            int rr = brow + (a >> 7);
            rA4[p] = rr < M ? rr : M - 1;   // clamp; garbage rows masked at store
            eA4[p] = (a & 127) >> 2;        // fp32 elem offset
        }
    } else {
#pragma unroll
        for (int p = 0; p < 2; ++p) rA2[p] = brow + row8[p];  // < NROW, padded bufs
    }
    const float*    A32 = (const float*)Ap;
    const _Float16* Af  = (const _Float16*)Ap;

    auto STAGE = [&](int buf, int k0) {     // MODE1: 6 loads, else 4
        char* bb = lds + buf * BUFB;
        if constexpr (MODE == 1) {
#pragma unroll
            for (int p = 0; p < 4; ++p) {
                int kk = k0 + eA4[p];
                if (kk >= K) kk = 0;        // tail cols hit W zero-pad -> product 0
                GLDS16(A32 + (size_t)rA4[p] * lda + kk, bb + p * 4096 + tid * 16);
            }
        } else {
#pragma unroll
            for (int p = 0; p < 2; ++p)
                GLDS16(Af + (size_t)rA2[p] * lda + k0 + ecol[p], bb + p * 4096 + tid * 16);
        }
#pragma unroll
        for (int p = 0; p < 2; ++p)
            GLDS16(Whi + (size_t)rB[p] * Kpad + k0 + ecol[p], bb + WOFF + p * 4096 + tid * 16);
    };

    // fragment read offsets (swizzled)
    int aoff[4], boff[4];
#pragma unroll
    for (int m = 0; m < 4; ++m) {
        int row = wr * 64 + m * 16 + l4;
        aoff[m] = (MODE == 1) ? swzA32(row * 128 + kg * 32) : swz(row * 64 + kg * 16);
        boff[m] = swz((wc * 64 + m * 16 + l4) * 64 + kg * 16);
    }

    f32x4 acc[4][4];
#pragma unroll
    for (int m = 0; m < 4; ++m)
#pragma unroll
        for (int n = 0; n < 4; ++n) acc[m][n] = (f32x4)(0.f);

    const int nk = Kpad / 32;
    STAGE(0, 0);

    for (int t = 0; t < nk; ++t) {
        if (t + 1 < nk) {
            STAGE((t + 1) & 1, (t + 1) * 32);                    // prefetch in flight
            if constexpr (MODE == 1)
                asm volatile("s_waitcnt vmcnt(6)" ::: "memory"); // wait this tile only
            else
                asm volatile("s_waitcnt vmcnt(4)" ::: "memory");
        } else {
            asm volatile("s_waitcnt vmcnt(0)" ::: "memory");     // tail drain
        }
        __builtin_amdgcn_s_barrier();
        __builtin_amdgcn_sched_barrier(0);

        char* bb = lds + (t & 1) * BUFB;
        f16x8 av[4], wh[4];
        if constexpr (MODE == 1) {
            // split-wait cvt hiding (r13)
            f32x4 u0[4], u1[4];
#pragma unroll
            for (int m = 0; m < 4; ++m) {            // 8 ds_read_b128 (A)
                u0[m] = *(const f32x4*)(bb + aoff[m]);
                u1[m] = *(const f32x4*)(bb + (aoff[m] ^ 16));
            }
            __builtin_amdgcn_sched_barrier(0);
#pragma unroll
            for (int n = 0; n < 4; ++n)              // 4 ds_read_b128 (W)
                wh[n] = *(const f16x8*)(bb + WOFF + boff[n]);
            __builtin_amdgcn_sched_barrier(0);
            asm volatile("s_waitcnt lgkmcnt(4)" ::: "memory");   // A complete
            __builtin_amdgcn_sched_barrier(0);
#pragma unroll
            for (int m = 0; m < 4; ++m) {            // cvt overlaps W drain
                av[m][0] = (_Float16)u0[m].x; av[m][1] = (_Float16)u0[m].y;
                av[m][2] = (_Float16)u0[m].z; av[m][3] = (_Float16)u0[m].w;
                av[m][4] = (_Float16)u1[m].x; av[m][5] = (_Float16)u1[m].y;
                av[m][6] = (_Float16)u1[m].z; av[m][7] = (_Float16)u1[m].w;
            }
        } else {
#pragma unroll
            for (int m = 0; m < 4; ++m) av[m] = *(const f16x8*)(bb + aoff[m]);
#pragma unroll
            for (int n = 0; n < 4; ++n) wh[n] = *(const f16x8*)(bb + WOFF + boff[n]);
        }
        asm volatile("s_waitcnt lgkmcnt(0)" ::: "memory");
        __builtin_amdgcn_sched_barrier(0);

#pragma unroll
        for (int m = 0; m < 4; ++m)
#pragma unroll
            for (int n = 0; n < 4; ++n)
                acc[m][n] = __builtin_amdgcn_mfma_f32_16x16x32_f16(av[m], wh[n], acc[m][n], 0, 0, 0);
        __builtin_amdgcn_s_barrier();
    }

    // ---- fused epilogue: C store + a_s/a_d partial dots ----
    // att weights for this thread's 4 columns (loop-invariant over rows)
    float atS[4], atD[4];
    int   hn[4];
#pragma unroll
    for (int n = 0; n < 4; ++n) {
        int gc = bcol + wc * 64 + n * 16 + l4;
        int hd = gc / CD;
        hn[n]  = hd;
        atS[n] = att_s[hd * CD + (gc - hd * CD)];
        atD[n] = att_d[hd * CD + (gc - hd * CD)];
    }

#pragma unroll
    for (int m = 0; m < 4; ++m) {
        int gr0 = brow + wr * 64 + m * 16 + (lane >> 4) * 4;
#pragma unroll
        for (int rr2 = 0; rr2 < 4; ++rr2) {
            int gr = gr0 + rr2;
            float v0 = acc[m][0][rr2], v1 = acc[m][1][rr2];
            float v2 = acc[m][2][rr2], v3 = acc[m][3][rr2];
            if (gr < M) {
                size_t ob = (size_t)gr * N + bcol + wc * 64 + l4;
                if constexpr (MODE == 2) {
                    float* C32 = (float*)Cp;
                    C32[ob] = v0; C32[ob + 16] = v1; C32[ob + 32] = v2; C32[ob + 48] = v3;
                } else {
                    _Float16* C16 = (_Float16*)Cp;
                    C16[ob] = (_Float16)v0; C16[ob + 16] = (_Float16)v1;
                    C16[ob + 32] = (_Float16)v2; C16[ob + 48] = (_Float16)v3;
                }
            }
            // partial dots, grouped by head-bucket {n0,n1} / {n2,n3}
            float ps0 = v0 * atS[0] + v1 * atS[1];
            float ps1 = v2 * atS[2] + v3 * atS[3];
            float pd0 = v0 * atD[0] + v1 * atD[1];
            float pd1 = v2 * atD[2] + v3 * atD[3];
#pragma unroll
            for (int o2 = 1; o2 < 16; o2 <<= 1) {
                ps0 += __shfl_xor(ps0, o2);
                ps1 += __shfl_xor(ps1, o2);
                pd0 += __shfl_xor(pd0, o2);
                pd1 += __shfl_xor(pd1, o2);
            }
            if (l4 == 0 && gr < M) {
                if (hn[0] == hn[2]) {
                    atomicAdd(&a_s[gr * GH + hn[0]], ps0 + ps1);
                    atomicAdd(&a_d[gr * GH + hn[0]], pd0 + pd1);
                } else {
                    atomicAdd(&a_s[gr * GH + hn[0]], ps0);
                    atomicAdd(&a_s[gr * GH + hn[2]], ps1);
                    atomicAdd(&a_d[gr * GH + hn[0]], pd0);
                    atomicAdd(&a_d[gr * GH + hn[2]], pd1);
                }
            }
        }
    }
}

// ---------------------------------------------------------------------------
// Softmax + aggregation, fp16 h input, CPT channels/thread (2 or 4).
// Output: fp16 activations (bias + ELU applied) = next GEMM's A operand.
// ---------------------------------------------------------------------------
template <int C, int CPT, int BLOCK>
__global__ __launch_bounds__(BLOCK) void gat_aggregate_f16(
        const unsigned short* __restrict__ hfeat,
        const float* __restrict__ a_s,
        const float* __restrict__ a_d,
        const int* __restrict__ offsets,
        const int* __restrict__ csr_src,
        const float* __restrict__ bias,
        unsigned short* __restrict__ of16) {
    constexpr int HC = GH * C;
    static_assert(BLOCK * CPT == HC, "coverage");
    const int n     = blockIdx.x;
    const int tid   = threadIdx.x;
    const int start = offsets[n];
    const int end   = offsets[n + 1];

    __shared__ float s_m[GH];
    __shared__ float s_den[GH];
    __shared__ int   s_src[64];
    __shared__ float s_al[GH][68];

    const float4 ad4 = *(const float4*)(a_d + n * GH);
    const float adh[GH] = {ad4.x, ad4.y, ad4.z, ad4.w};

    if (tid < 64) {
        float lmax[GH], lsum[GH];
#pragma unroll
        for (int h = 0; h < GH; ++h) lmax[h] = -1e30f;
        for (int e = start + tid; e < end; e += 64) {
            int s = csr_src[e];
            float4 as4 = *(const float4*)(a_s + s * GH);
            float l[GH] = {as4.x + adh[0], as4.y + adh[1], as4.z + adh[2], as4.w + adh[3]};
#pragma unroll
            for (int h = 0; h < GH; ++h) {
                float ll = l[h] > 0.f ? l[h] : 0.2f * l[h];
                lmax[h] = fmaxf(lmax[h], ll);
            }
        }
#pragma unroll
        for (int h = 0; h < GH; ++h)
#pragma unroll
            for (int o = 32; o; o >>= 1) lmax[h] = fmaxf(lmax[h], __shfl_xor(lmax[h], o));
#pragma unroll
        for (int h = 0; h < GH; ++h) lsum[h] = 0.f;
        for (int e = start + tid; e < end; e += 64) {
            int s = csr_src[e];
            float4 as4 = *(const float4*)(a_s + s * GH);
            float l[GH] = {as4.x + adh[0], as4.y + adh[1], as4.z + adh[2], as4.w + adh[3]};
#pragma unroll
            for (int h = 0; h < GH; ++h) {
                float ll = l[h] > 0.f ? l[h] : 0.2f * l[h];
                lsum[h] += __expf(ll - lmax[h]);
            }
        }
#pragma unroll
        for (int h = 0; h < GH; ++h)
#pragma unroll
            for (int o = 32; o; o >>= 1) lsum[h] += __shfl_xor(lsum[h], o);
        if (tid == 0) {
#pragma unroll
            for (int h = 0; h < GH; ++h) { s_m[h] = lmax[h]; s_den[h] = lsum[h]; }
        }
    }
    __syncthreads();

    float mm[GH], inv[GH];
#pragma unroll
    for (int h = 0; h < GH; ++h) { mm[h] = s_m[h]; inv[h] = 1.0f / s_den[h]; }

    const int ch0 = tid * CPT;
    const int hd  = ch0 / C;
    float acc[CPT];
#pragma unroll
    for (int j = 0; j < CPT; ++j) acc[j] = 0.f;

    for (int e0 = start; e0 < end; e0 += 64) {
        __syncthreads();
        if (tid < 64) {
            bool vld = (e0 + tid) < end;
            int s = vld ? csr_src[e0 + tid] : n;
            s_src[tid] = s;
            float4 as4 = *(const float4*)(a_s + s * GH);
            float l[GH] = {as4.x + adh[0], as4.y + adh[1], as4.z + adh[2], as4.w + adh[3]};
#pragma unroll
            for (int h = 0; h < GH; ++h) {
                float ll = l[h] > 0.f ? l[h] : 0.2f * l[h];
                s_al[h][tid] = vld ? __expf(ll - mm[h]) * inv[h] : 0.f;
            }
        }
        __syncthreads();
        int cnt = end - e0; if (cnt > 64) cnt = 64;
        int cnt4 = (cnt + 3) & ~3;
        for (int i = 0; i < cnt4; i += 4) {
            int4   ss = *(const int4*)&s_src[i];
            float4 aa = *(const float4*)&s_al[hd][i];
            if constexpr (CPT == 4) {
                uint2 v0 = ((const uint2*)(hfeat + (size_t)ss.x * HC))[tid];
                uint2 v1 = ((const uint2*)(hfeat + (size_t)ss.y * HC))[tid];
                uint2 v2 = ((const uint2*)(hfeat + (size_t)ss.z * HC))[tid];
                uint2 v3 = ((const uint2*)(hfeat + (size_t)ss.w * HC))[tid];
                acc[0] = fmaf(aa.x, h2f(v0.x & 0xffff), acc[0]);
                acc[1] = fmaf(aa.x, h2f(v0.x >> 16),    acc[1]);
                acc[2] = fmaf(aa.x, h2f(v0.y & 0xffff), acc[2]);
                acc[3] = fmaf(aa.x, h2f(v0.y >> 16),    acc[3]);
                acc[0] = fmaf(aa.y, h2f(v1.x & 0xffff), acc[0]);
                acc[1] = fmaf(aa.y, h2f(v1.x >> 16),    acc[1]);
                acc[2] = fmaf(aa.y, h2f(v1.y & 0xffff), acc[2]);
                acc[3] = fmaf(aa.y, h2f(v1.y >> 16),    acc[3]);
                acc[0] = fmaf(aa.z, h2f(v2.x & 0xffff), acc[0]);
                acc[1] = fmaf(aa.z, h2f(v2.x >> 16),    acc[1]);
                acc[2] = fmaf(aa.z, h2f(v2.y & 0xffff), acc[2]);
                acc[3] = fmaf(aa.z, h2f(v2.y >> 16),    acc[3]);
                acc[0] = fmaf(aa.w, h2f(v3.x & 0xffff), acc[0]);
                acc[1] = fmaf(aa.w, h2f(v3.x >> 16),    acc[1]);
                acc[2] = fmaf(aa.w, h2f(v3.y & 0xffff), acc[2]);
                acc[3] = fmaf(aa.w, h2f(v3.y >> 16),    acc[3]);
            } else {
                unsigned v0 = ((const unsigned*)(hfeat + (size_t)ss.x * HC))[tid];
                unsigned v1 = ((const unsigned*)(hfeat + (size_t)ss.y * HC))[tid];
                unsigned v2 = ((const unsigned*)(hfeat + (size_t)ss.z * HC))[tid];
                unsigned v3 = ((const unsigned*)(hfeat + (size_t)ss.w * HC))[tid];
                acc[0] = fmaf(aa.x, h2f(v0 & 0xffff), acc[0]);
                acc[1] = fmaf(aa.x, h2f(v0 >> 16),    acc[1]);
                acc[0] = fmaf(aa.y, h2f(v1 & 0xffff), acc[0]);
                acc[1] = fmaf(aa.y, h2f(v1 >> 16),    acc[1]);
                acc[0] = fmaf(aa.z, h2f(v2 & 0xffff), acc[0]);
                acc[1] = fmaf(aa.z, h2f(v2 >> 16),    acc[1]);
                acc[0] = fmaf(aa.w, h2f(v3 & 0xffff), acc[0]);
                acc[1] = fmaf(aa.w, h2f(v3 >> 16),    acc[1]);
            }
        }
    }

    // epilogue: bias + ELU -> fp16
    unsigned short hs[CPT];
#pragma unroll
    for (int j = 0; j < CPT; ++j) {
        float v = acc[j] + bias[ch0 + j];
        v = v > 0.f ? v : expm1f(v);
        hs[j] = f2h_bits(v);
    }
    unsigned short* op = of16 + (size_t)n * HC + ch0;
    if constexpr (CPT == 4) {
        uint2 hw = make_uint2((unsigned)hs[0] | ((unsigned)hs[1] << 16),
                              (unsigned)hs[2] | ((unsigned)hs[3] << 16));
        *(uint2*)op = hw;
    } else {
        *(unsigned*)op = (unsigned)hs[0] | ((unsigned)hs[1] << 16);
    }
}

// ---------------------------------------------------------------------------
// Final layer aggregation: fp32 h input, head-mean + bias -> fp32 d_out.
// ---------------------------------------------------------------------------
__global__ __launch_bounds__(128) void gat_aggregate_final(
        const float* __restrict__ hfeat,
        const float* __restrict__ a_s,
        const float* __restrict__ a_d,
        const int* __restrict__ offsets,
        const int* __restrict__ csr_src,
        const float* __restrict__ bias,
        float* __restrict__ outf) {
    constexpr int C = 64, HC = GH * C;
    const int n     = blockIdx.x;
    const int tid   = threadIdx.x;
    const int start = offsets[n];
    const int end   = offsets[n + 1];

    __shared__ float s_m[GH];
    __shared__ float s_den[GH];
    __shared__ int   s_src[64];
    __shared__ float s_al[GH][68];
    __shared__ float sacc[256];

    const float4 ad4 = *(const float4*)(a_d + n * GH);
    const float adh[GH] = {ad4.x, ad4.y, ad4.z, ad4.w};

    if (tid < 64) {
        float lmax[GH], lsum[GH];
#pragma unroll
        for (int h = 0; h < GH; ++h) lmax[h] = -1e30f;
        for (int e = start + tid; e < end; e += 64) {
            int s = csr_src[e];
            float4 as4 = *(const float4*)(a_s + s * GH);
            float l[GH] = {as4.x + adh[0], as4.y + adh[1], as4.z + adh[2], as4.w + adh[3]};
#pragma unroll
            for (int h = 0; h < GH; ++h) {
                float ll = l[h] > 0.f ? l[h] : 0.2f * l[h];
                lmax[h] = fmaxf(lmax[h], ll);
            }
        }
#pragma unroll
        for (int h = 0; h < GH; ++h)
#pragma unroll
            for (int o = 32; o; o >>= 1) lmax[h] = fmaxf(lmax[h], __shfl_xor(lmax[h], o));
#pragma unroll
        for (int h = 0; h < GH; ++h) lsum[h] = 0.f;
        for (int e = start + tid; e < end; e += 64) {
            int s = csr_src[e];
            float4 as4 = *(const float4*)(a_s + s * GH);
            float l[GH] = {as4.x + adh[0], as4.y + adh[1], as4.z + adh[2], as4.w + adh[3]};
#pragma unroll
            for (int h = 0; h < GH; ++h) {
                float ll = l[h] > 0.f ? l[h] : 0.2f * l[h];
                lsum[h] += __expf(ll - lmax[h]);
            }
        }
#pragma unroll
        for (int h = 0; h < GH; ++h)
#pragma unroll
            for (int o = 32; o; o >>= 1) lsum[h] += __shfl_xor(lsum[h], o);
        if (tid == 0) {
#pragma unroll
            for (int h = 0; h < GH; ++h) { s_m[h] = lmax[h]; s_den[h] = lsum[h]; }
        }
    }
    __syncthreads();

    float mm[GH], inv[GH];
#pragma unroll
    for (int h = 0; h < GH; ++h) { mm[h] = s_m[h]; inv[h] = 1.0f / s_den[h]; }

    const int hd = (2 * tid) / C;
    float2 acc = make_float2(0.f, 0.f);

    for (int e0 = start; e0 < end; e0 += 64) {
        __syncthreads();
        if (tid < 64) {
            bool vld = (e0 + tid) < end;
            int s = vld ? csr_src[e0 + tid] : n;
            s_src[tid] = s;
            float4 as4 = *(const float4*)(a_s + s * GH);
            float l[GH] = {as4.x + adh[0], as4.y + adh[1], as4.z + adh[2], as4.w + adh[3]};
#pragma unroll
            for (int h = 0; h < GH; ++h) {
                float ll = l[h] > 0.f ? l[h] : 0.2f * l[h];
                s_al[h][tid] = vld ? __expf(ll - mm[h]) * inv[h] : 0.f;
            }
        }
        __syncthreads();
        int cnt = end - e0; if (cnt > 64) cnt = 64;
        int cnt4 = (cnt + 3) & ~3;
        for (int i = 0; i < cnt4; i += 4) {
            int4   ss = *(const int4*)&s_src[i];
            float4 aa = *(const float4*)&s_al[hd][i];
            float2 v0 = ((const float2*)(hfeat + (size_t)ss.x * HC))[tid];
            float2 v1 = ((const float2*)(hfeat + (size_t)ss.y * HC))[tid];
            float2 v2 = ((const float2*)(hfeat + (size_t)ss.z * HC))[tid];
            float2 v3 = ((const float2*)(hfeat + (size_t)ss.w * HC))[tid];
            acc.x = fmaf(aa.x, v0.x, acc.x); acc.y = fmaf(aa.x, v0.y, acc.y);
            acc.x = fmaf(aa.y, v1.x, acc.x); acc.y = fmaf(aa.y, v1.y, acc.y);
            acc.x = fmaf(aa.z, v2.x, acc.x); acc.y = fmaf(aa.z, v2.y, acc.y);
            acc.x = fmaf(aa.w, v3.x, acc.x); acc.y = fmaf(aa.w, v3.y, acc.y);
        }
    }

    sacc[2 * tid]     = acc.x;
    sacc[2 * tid + 1] = acc.y;
    __syncthreads();
    if (tid < C) {
        float v = 0.f;
#pragma unroll
        for (int h = 0; h < GH; ++h) v += sacc[h * C + tid];
        outf[(size_t)n * C + tid] = v * (1.0f / GH) + bias[tid];
    }
}

// ---------------------------------------------------------------------------
extern "C" void kernel_launch(void* const* d_in, const int* in_sizes, int n_in,
                              void* d_out, int out_size, void* d_ws, size_t ws_size,
                              hipStream_t stream) {
    const float* x  = (const float*)d_in[0];
    const void*  ei = d_in[1];
    const float* W[4]  = {(const float*)d_in[2],  (const float*)d_in[6],
                          (const float*)d_in[10], (const float*)d_in[14]};
    const float* AS[4] = {(const float*)d_in[3],  (const float*)d_in[7],
                          (const float*)d_in[11], (const float*)d_in[15]};
    const float* AD[4] = {(const float*)d_in[4],  (const float*)d_in[8],
                          (const float*)d_in[12], (const float*)d_in[16]};
    const float* BI[4] = {(const float*)d_in[5],  (const float*)d_in[9],
                          (const float*)d_in[13], (const float*)d_in[17]};

    char*  w   = (char*)d_ws;
    size_t off = 0;
    auto alloc = [&](size_t b) -> char* {
        char* p = w + off;
        off += (b + 255) & ~(size_t)255;
        return p;
    };
    int*   flag    = (int*)alloc(4);
    int*   counts  = (int*)alloc((GN + 1) * sizeof(int));
    int*   offsets = (int*)alloc((GN + 1) * sizeof(int));
    int*   cursor  = (int*)alloc(GN * sizeof(int));
    int*   csr_src = (int*)alloc((size_t)GETOT * sizeof(int));
    // 4 layer-pairs of (a_s, a_d), contiguous -> one memset zeroes all
    float* attb    = (float*)alloc((size_t)8 * GN * GH * sizeof(float));   // 2.56 MB
    float* aS[4], *aD[4];
    for (int i = 0; i < 4; ++i) {
        aS[i] = attb + (size_t)(2 * i)     * GN * GH;
        aD[i] = attb + (size_t)(2 * i + 1) * GN * GH;
    }
    unsigned short* hA = (unsigned short*)alloc((size_t)NROW * 512 * 2);   // GEMM out h (fp16)
    unsigned short* hB = (unsigned short*)alloc((size_t)NROW * 512 * 2);   // agg out act (fp16)
    float* hbuf    = (float*)alloc((size_t)NROW * 256 * sizeof(float));    // L3 fp32 h
    _Float16* wt   = (_Float16*)alloc((size_t)512 * 2016 * 2);             // 2.06 MB
    (void)in_sizes; (void)n_in; (void)out_size; (void)ws_size;

    // ---- CSR by destination (layer-invariant) + zero att accumulators ----
    detect_dtype_kernel<<<1, 64, 0, stream>>>(ei, flag);
    hipMemsetAsync(counts, 0, (GN + 1) * sizeof(int), stream);
    hipMemsetAsync(attb, 0, (size_t)8 * GN * GH * sizeof(float), stream);
    int eblocks = (GETOT + 255) / 256;
    hist_kernel<<<eblocks, 256, 0, stream>>>(ei, flag, counts);
    scan_kernel<<<1, 1024, 0, stream>>>(counts, offsets, cursor);
    scatter_kernel<<<eblocks, 256, 0, stream>>>(ei, flag, cursor, csr_src);

    const dim3 tb(32, 8);
    const int NR = (GN + 127) / 128;   // 157 row blocks

    // ---- layer 0: 2000 -> 4x128 concat, ELU (A = fp32 x direct, MODE1) ----
    convert_wt<<<dim3(2016 / 32, 512 / 32), tb, 0, stream>>>(W[0], wt, 2000, 512, 2016);
    gemm_f16<1, 128><<<NR * 4, 256, 0, stream>>>(x, 2000, 2000, wt, 2016, hA, GN, 512, 4,
                                                 AS[0], AD[0], aS[0], aD[0]);
    gat_aggregate_f16<128, 4, 128><<<GN, 128, 0, stream>>>(hA, aS[0], aD[0], offsets, csr_src,
                                                           BI[0], hB);
    // ---- layer 1: 512 -> 4x64 concat, ELU ----
    convert_wt<<<dim3(512 / 32, 256 / 32), tb, 0, stream>>>(W[1], wt, 512, 256, 512);
    gemm_f16<0, 64><<<NR * 2, 256, 0, stream>>>(hB, 512, 512, wt, 512, hA, GN, 256, 2,
                                                AS[1], AD[1], aS[1], aD[1]);
    gat_aggregate_f16<64, 4, 64><<<GN, 64, 0, stream>>>(hA, aS[1], aD[1], offsets, csr_src,
                                                        BI[1], hB);
    // ---- layer 2: 256 -> 4x32 concat, ELU ----
    convert_wt<<<dim3(256 / 32, 128 / 32), tb, 0, stream>>>(W[2], wt, 256, 128, 256);
    gemm_f16<0, 32><<<NR * 1, 256, 0, stream>>>(hB, 256, 256, wt, 256, hA, GN, 128, 1,
                                                AS[2], AD[2], aS[2], aD[2]);
    gat_aggregate_f16<32, 2, 64><<<GN, 64, 0, stream>>>(hA, aS[2], aD[2], offsets, csr_src,
                                                        BI[2], hB);
    // ---- layer 3: 128 -> 4x64 mean, no ELU (fp32 h for output fidelity) ----
    convert_wt<<<dim3(128 / 32, 256 / 32), tb, 0, stream>>>(W[3], wt, 128, 256, 128);
    gemm_f16<2, 64><<<NR * 2, 256, 0, stream>>>(hB, 128, 128, wt, 128, hbuf, GN, 256, 2,
                                                AS[3], AD[3], aS[3], aD[3]);
    gat_aggregate_final<<<GN, 128, 0, stream>>>(hbuf, aS[3], aD[3], offsets, csr_src,
                                                BI[3], (float*)d_out);
}

// Round 16
// 384.012 us; speedup vs baseline: 1.1093x; 1.0373x over previous
//
#include <hip/hip_runtime.h>
#include <hip/hip_bf16.h>

#define GN 20000          // nodes
#define GE 320000         // edges (without self loops)
#define GETOT (GE + GN)   // edges + self loops
#define GH 4              // heads
#define NROW 20096        // padded row count (staging over-read safety, 157*128)

typedef __attribute__((ext_vector_type(8))) _Float16 f16x8;  // 8 fp16 = 4 VGPR
typedef __attribute__((ext_vector_type(4))) float f32x4;

// ---------------------------------------------------------------------------
// edge_index dtype detection (int64 vs x64-disabled int32)
// ---------------------------------------------------------------------------
__global__ void detect_dtype_kernel(const void* __restrict__ ei, int* __restrict__ flag) {
    if (threadIdx.x == 0 && blockIdx.x == 0) {
        const long long* p = (const long long*)ei;
        int ok = 1;
        for (int i = 0; i < 16; ++i) {
            long long v = p[i];
            if (v < 0 || v >= GN) ok = 0;
        }
        *flag = ok;
    }
}

__device__ __forceinline__ int load_idx(const void* ei, int is64, long long pos) {
    if (is64) return (int)((const long long*)ei)[pos];
    return ((const int*)ei)[pos];
}

// ---------------------------------------------------------------------------
// CSR build
// ---------------------------------------------------------------------------
__global__ void hist_kernel(const void* __restrict__ ei, const int* __restrict__ flagp,
                            int* __restrict__ counts) {
    int e = blockIdx.x * blockDim.x + threadIdx.x;
    if (e >= GETOT) return;
    int d;
    if (e < GE) d = load_idx(ei, *flagp, (long long)GE + e);
    else        d = e - GE;
    atomicAdd(&counts[d], 1);
}

// 20000-element exclusive scan: 20 serial elems/thread + ONE 1024-wide scan.
__global__ __launch_bounds__(1024) void scan_kernel(const int* __restrict__ counts,
                                                    int* __restrict__ offsets,
                                                    int* __restrict__ cursor) {
    __shared__ int sh[1024];
    const int tid = threadIdx.x;
    constexpr int CH = 20;                 // 1024*20 = 20480 >= GN
    const int base = tid * CH;
    int loc[CH];
    int sum = 0;
#pragma unroll
    for (int i = 0; i < CH; ++i) {
        int idx = base + i;
        int v = (idx < GN) ? counts[idx] : 0;
        loc[i] = sum;                      // exclusive prefix within chunk
        sum += v;
    }
    sh[tid] = sum;
    __syncthreads();
    for (int o = 1; o < 1024; o <<= 1) {   // 10 steps, 20 barriers total
        int t = (tid >= o) ? sh[tid - o] : 0;
        __syncthreads();
        sh[tid] += t;
        __syncthreads();
    }
    const int excl = tid ? sh[tid - 1] : 0;
#pragma unroll
    for (int i = 0; i < CH; ++i) {
        int idx = base + i;
        if (idx < GN) {
            int o = excl + loc[i];
            offsets[idx] = o;
            cursor[idx]  = o;
        }
    }
    if (tid == 1023) offsets[GN] = sh[1023];
}

__global__ void scatter_kernel(const void* __restrict__ ei, const int* __restrict__ flagp,
                               int* __restrict__ cursor, int* __restrict__ csr_src) {
    int e = blockIdx.x * blockDim.x + threadIdx.x;
    if (e >= GETOT) return;
    int s, d;
    if (e < GE) {
        int is64 = *flagp;
        s = load_idx(ei, is64, e);
        d = load_idx(ei, is64, (long long)GE + e);
    } else {
        s = d = e - GE;
    }
    int pos = atomicAdd(&cursor[d], 1);
    csr_src[pos] = s;
}

// ---------------------------------------------------------------------------
// fp16 helpers
// ---------------------------------------------------------------------------
__device__ __forceinline__ float h2f(unsigned u) {
    unsigned short us = (unsigned short)u;
    _Float16 h;
    __builtin_memcpy(&h, &us, 2);
    return (float)h;
}
__device__ __forceinline__ unsigned short f2h_bits(float v) {
    _Float16 h = (_Float16)v;
    unsigned short us;
    __builtin_memcpy(&us, &h, 2);
    return us;
}

// W fp32 [K][N] -> Wt fp16 [N][Kpad] (transposed, zero-padded K)
__global__ void convert_wt(const float* __restrict__ W,
                           _Float16* __restrict__ thi,
                           int K, int N, int Kpad) {
    __shared__ float tile[32][33];
    int kb = blockIdx.x * 32, nb = blockIdx.y * 32;
    for (int i = threadIdx.y; i < 32; i += 8) {
        int k = kb + i, n = nb + threadIdx.x;
        tile[i][threadIdx.x] = (k < K) ? W[(size_t)k * N + n] : 0.f;
    }
    __syncthreads();
    for (int i = threadIdx.y; i < 32; i += 8) {
        int n = nb + i, k = kb + threadIdx.x;
        thi[(size_t)n * Kpad + k] = (_Float16)tile[threadIdx.x][i];
    }
}

// ---------------------------------------------------------------------------
// LDS swizzles.
// 16-bit tiles (64B rows): phys = a ^ (((a>>6)&7)<<4)   [proven r2-r15]
// fp32 tiles (128B rows):  phys = a ^ (((a>>7)&7)<<4)   (involution, r5-r15)
// ---------------------------------------------------------------------------
__device__ __forceinline__ int swz(int a) { return a ^ (((a >> 6) & 7) << 4); }
__device__ __forceinline__ int invswz(int p) {
    int b8 = (p >> 8) & 1, b7 = (p >> 7) & 1;
    int a6 = ((p >> 6) & 1) ^ b8;
    int a5 = ((p >> 5) & 1) ^ b7;
    int a4 = ((p >> 4) & 1) ^ a6;
    return (p & ~0x70) | (a4 << 4) | (a5 << 5) | (a6 << 6);
}
__device__ __forceinline__ int swzA32(int a) { return a ^ (((a >> 7) & 7) << 4); }

#define GLDS16(gsrc, ldst) __builtin_amdgcn_global_load_lds( \
    (const __attribute__((address_space(1))) void*)(gsrc),   \
    (__attribute__((address_space(3))) void*)(ldst), 16, 0, 0)

// ---------------------------------------------------------------------------
// fp16 1-pass MFMA GEMM with FUSED a_s/a_d epilogue.
// C = A @ W_fp16 (fp32 accumulate); BM=128, BN=128, BK=32, 4 waves (2x2).
// MODE 0: A fp16 (DMA), C fp16.    MODE 1: A fp32 direct (L0), C fp16.
// r16: ONE barrier per K-step. Safety: every wave lgkmcnt(0)-drains its
// buf[t-1] ds_reads before MFMA (iter t-1), hence before barrier(t); so
// after barrier(t) the STAGE(t+1) DMA may overwrite buf[t+1]==buf[t-1].
// vmcnt(0) before the barrier drains each wave's OWN tile-t loads (only
// those are outstanding at that point — STAGE(t+1) is issued after).
// ---------------------------------------------------------------------------
template <int MODE, int CD>
__global__ __launch_bounds__(256, MODE == 1 ? 3 : 4) void gemm_f16(
        const void* __restrict__ Ap, int lda, int K,
        const _Float16* __restrict__ Whi,
        int Kpad, void* __restrict__ Cp, int M, int N, int NC,
        const float* __restrict__ att_s, const float* __restrict__ att_d,
        float* __restrict__ a_s, float* __restrict__ a_d) {
    constexpr int BUFB = (MODE == 1) ? 24576 : 16384;
    constexpr int WOFF = (MODE == 1) ? 16384 : 8192;
    __shared__ char lds[2 * BUFB];
    const int tid = threadIdx.x;

    // bijective XCD-chunked remap (m204), row-major work order
    const int nwg = gridDim.x;
    const int q = nwg >> 3, r = nwg & 7;
    const int xcd = blockIdx.x & 7, sub = blockIdx.x >> 3;
    const int orig = (xcd < r ? xcd * (q + 1) : r * (q + 1) + (xcd - r) * q) + sub;
    const int brow = (orig / NC) * 128;
    const int bcol = (orig % NC) * 128;

    const int lane = tid & 63, wid = tid >> 6;
    const int wr = wid >> 1, wc = wid & 1;
    const int l4 = lane & 15, kg = lane >> 4;

    // W staging map (fp16 tile, 2 passes)
    int row8[2], ecol[2];
#pragma unroll
    for (int p = 0; p < 2; ++p) {
        int a = invswz(p * 4096 + tid * 16);
        row8[p] = a >> 6;
        ecol[p] = (a & 63) >> 1;
    }
    int rB[2];
#pragma unroll
    for (int p = 0; p < 2; ++p) rB[p] = bcol + row8[p];   // N % 128 == 0 -> valid

    // A staging map
    int rA2[2];                     // MODE 0 (fp16, 2 passes)
    int rA4[4], eA4[4];             // MODE 1 (fp32, 4 passes)
    if constexpr (MODE == 1) {
#pragma unroll
        for (int p = 0; p < 4; ++p) {
            int a = swzA32(p * 4096 + tid * 16);
            int rr = brow + (a >> 7);
            rA4[p] = rr < M ? rr : M - 1;   // clamp; garbage rows masked at store
            eA4[p] = (a & 127) >> 2;        // fp32 elem offset
        }
    } else {
#pragma unroll
        for (int p = 0; p < 2; ++p) rA2[p] = brow + row8[p];  // < NROW, padded bufs
    }
    const float*    A32 = (const float*)Ap;
    const _Float16* Af  = (const _Float16*)Ap;

    auto STAGE = [&](int buf, int k0) {     // MODE1: 6 loads, else 4
        char* bb = lds + buf * BUFB;
        if constexpr (MODE == 1) {
#pragma unroll
            for (int p = 0; p < 4; ++p) {
                int kk = k0 + eA4[p];
                if (kk >= K) kk = 0;        // tail cols hit W zero-pad -> product 0
                GLDS16(A32 + (size_t)rA4[p] * lda + kk, bb + p * 4096 + tid * 16);
            }
        } else {
#pragma unroll
            for (int p = 0; p < 2; ++p)
                GLDS16(Af + (size_t)rA2[p] * lda + k0 + ecol[p], bb + p * 4096 + tid * 16);
        }
#pragma unroll
        for (int p = 0; p < 2; ++p)
            GLDS16(Whi + (size_t)rB[p] * Kpad + k0 + ecol[p], bb + WOFF + p * 4096 + tid * 16);
    };

    // fragment read offsets (swizzled)
    int aoff[4], boff[4];
#pragma unroll
    for (int m = 0; m < 4; ++m) {
        int row = wr * 64 + m * 16 + l4;
        aoff[m] = (MODE == 1) ? swzA32(row * 128 + kg * 32) : swz(row * 64 + kg * 16);
        boff[m] = swz((wc * 64 + m * 16 + l4) * 64 + kg * 16);
    }

    f32x4 acc[4][4];
#pragma unroll
    for (int m = 0; m < 4; ++m)
#pragma unroll
        for (int n = 0; n < 4; ++n) acc[m][n] = (f32x4)(0.f);

    const int nk = Kpad / 32;
    STAGE(0, 0);

    for (int t = 0; t < nk; ++t) {
        asm volatile("s_waitcnt vmcnt(0)" ::: "memory");  // own tile-t loads done
        __builtin_amdgcn_s_barrier();                     // buf[t] ready; buf[t-1] free
        __builtin_amdgcn_sched_barrier(0);
        if (t + 1 < nk) STAGE((t + 1) & 1, (t + 1) * 32); // covered by this iter

        char* bb = lds + (t & 1) * BUFB;
        f16x8 av[4], wh[4];
        if constexpr (MODE == 1) {
            // split-wait cvt hiding (r13)
            f32x4 u0[4], u1[4];
#pragma unroll
            for (int m = 0; m < 4; ++m) {            // 8 ds_read_b128 (A)
                u0[m] = *(const f32x4*)(bb + aoff[m]);
                u1[m] = *(const f32x4*)(bb + (aoff[m] ^ 16));
            }
            __builtin_amdgcn_sched_barrier(0);
#pragma unroll
            for (int n = 0; n < 4; ++n)              // 4 ds_read_b128 (W)
                wh[n] = *(const f16x8*)(bb + WOFF + boff[n]);
            __builtin_amdgcn_sched_barrier(0);
            asm volatile("s_waitcnt lgkmcnt(4)" ::: "memory");   // A complete
            __builtin_amdgcn_sched_barrier(0);
#pragma unroll
            for (int m = 0; m < 4; ++m) {            // cvt overlaps W drain
                av[m][0] = (_Float16)u0[m].x; av[m][1] = (_Float16)u0[m].y;
                av[m][2] = (_Float16)u0[m].z; av[m][3] = (_Float16)u0[m].w;
                av[m][4] = (_Float16)u1[m].x; av[m][5] = (_Float16)u1[m].y;
                av[m][6] = (_Float16)u1[m].z; av[m][7] = (_Float16)u1[m].w;
            }
        } else {
#pragma unroll
            for (int m = 0; m < 4; ++m) av[m] = *(const f16x8*)(bb + aoff[m]);
#pragma unroll
            for (int n = 0; n < 4; ++n) wh[n] = *(const f16x8*)(bb + WOFF + boff[n]);
        }
        asm volatile("s_waitcnt lgkmcnt(0)" ::: "memory");
        __builtin_amdgcn_sched_barrier(0);

#pragma unroll
        for (int m = 0; m < 4; ++m)
#pragma unroll
            for (int n = 0; n < 4; ++n)
                acc[m][n] = __builtin_amdgcn_mfma_f32_16x16x32_f16(av[m], wh[n], acc[m][n], 0, 0, 0);
        // no trailing barrier: next iter's vmcnt+barrier provides the fence
    }

    // ---- fused epilogue: C store + a_s/a_d partial dots ----
    float atS[4], atD[4];
    int   hn[4];
#pragma unroll
    for (int n = 0; n < 4; ++n) {
        int gc = bcol + wc * 64 + n * 16 + l4;
        int hd = gc / CD;
        hn[n]  = hd;
        atS[n] = att_s[hd * CD + (gc - hd * CD)];
        atD[n] = att_d[hd * CD + (gc - hd * CD)];
    }

#pragma unroll
    for (int m = 0; m < 4; ++m) {
        int gr0 = brow + wr * 64 + m * 16 + (lane >> 4) * 4;
#pragma unroll
        for (int rr2 = 0; rr2 < 4; ++rr2) {
            int gr = gr0 + rr2;
            float v0 = acc[m][0][rr2], v1 = acc[m][1][rr2];
            float v2 = acc[m][2][rr2], v3 = acc[m][3][rr2];
            if (gr < M) {
                size_t ob = (size_t)gr * N + bcol + wc * 64 + l4;
                _Float16* C16 = (_Float16*)Cp;
                C16[ob] = (_Float16)v0; C16[ob + 16] = (_Float16)v1;
                C16[ob + 32] = (_Float16)v2; C16[ob + 48] = (_Float16)v3;
            }
            float ps0 = v0 * atS[0] + v1 * atS[1];
            float ps1 = v2 * atS[2] + v3 * atS[3];
            float pd0 = v0 * atD[0] + v1 * atD[1];
            float pd1 = v2 * atD[2] + v3 * atD[3];
#pragma unroll
            for (int o2 = 1; o2 < 16; o2 <<= 1) {
                ps0 += __shfl_xor(ps0, o2);
                ps1 += __shfl_xor(ps1, o2);
                pd0 += __shfl_xor(pd0, o2);
                pd1 += __shfl_xor(pd1, o2);
            }
            if (l4 == 0 && gr < M) {
                if (hn[0] == hn[2]) {
                    atomicAdd(&a_s[gr * GH + hn[0]], ps0 + ps1);
                    atomicAdd(&a_d[gr * GH + hn[0]], pd0 + pd1);
                } else {
                    atomicAdd(&a_s[gr * GH + hn[0]], ps0);
                    atomicAdd(&a_s[gr * GH + hn[2]], ps1);
                    atomicAdd(&a_d[gr * GH + hn[0]], pd0);
                    atomicAdd(&a_d[gr * GH + hn[2]], pd1);
                }
            }
        }
    }
}

// ---------------------------------------------------------------------------
// Softmax + aggregation, fp16 h input, CPT channels/thread (2 or 4).
// Output: fp16 activations (bias + ELU applied) = next GEMM's A operand.
// ---------------------------------------------------------------------------
template <int C, int CPT, int BLOCK>
__global__ __launch_bounds__(BLOCK) void gat_aggregate_f16(
        const unsigned short* __restrict__ hfeat,
        const float* __restrict__ a_s,
        const float* __restrict__ a_d,
        const int* __restrict__ offsets,
        const int* __restrict__ csr_src,
        const float* __restrict__ bias,
        unsigned short* __restrict__ of16) {
    constexpr int HC = GH * C;
    static_assert(BLOCK * CPT == HC, "coverage");
    const int n     = blockIdx.x;
    const int tid   = threadIdx.x;
    const int start = offsets[n];
    const int end   = offsets[n + 1];

    __shared__ float s_m[GH];
    __shared__ float s_den[GH];
    __shared__ int   s_src[64];
    __shared__ float s_al[GH][68];

    const float4 ad4 = *(const float4*)(a_d + n * GH);
    const float adh[GH] = {ad4.x, ad4.y, ad4.z, ad4.w};

    if (tid < 64) {
        float lmax[GH], lsum[GH];
#pragma unroll
        for (int h = 0; h < GH; ++h) lmax[h] = -1e30f;
        for (int e = start + tid; e < end; e += 64) {
            int s = csr_src[e];
            float4 as4 = *(const float4*)(a_s + s * GH);
            float l[GH] = {as4.x + adh[0], as4.y + adh[1], as4.z + adh[2], as4.w + adh[3]};
#pragma unroll
            for (int h = 0; h < GH; ++h) {
                float ll = l[h] > 0.f ? l[h] : 0.2f * l[h];
                lmax[h] = fmaxf(lmax[h], ll);
            }
        }
#pragma unroll
        for (int h = 0; h < GH; ++h)
#pragma unroll
            for (int o = 32; o; o >>= 1) lmax[h] = fmaxf(lmax[h], __shfl_xor(lmax[h], o));
#pragma unroll
        for (int h = 0; h < GH; ++h) lsum[h] = 0.f;
        for (int e = start + tid; e < end; e += 64) {
            int s = csr_src[e];
            float4 as4 = *(const float4*)(a_s + s * GH);
            float l[GH] = {as4.x + adh[0], as4.y + adh[1], as4.z + adh[2], as4.w + adh[3]};
#pragma unroll
            for (int h = 0; h < GH; ++h) {
                float ll = l[h] > 0.f ? l[h] : 0.2f * l[h];
                lsum[h] += __expf(ll - lmax[h]);
            }
        }
#pragma unroll
        for (int h = 0; h < GH; ++h)
#pragma unroll
            for (int o = 32; o; o >>= 1) lsum[h] += __shfl_xor(lsum[h], o);
        if (tid == 0) {
#pragma unroll
            for (int h = 0; h < GH; ++h) { s_m[h] = lmax[h]; s_den[h] = lsum[h]; }
        }
    }
    __syncthreads();

    float mm[GH], inv[GH];
#pragma unroll
    for (int h = 0; h < GH; ++h) { mm[h] = s_m[h]; inv[h] = 1.0f / s_den[h]; }

    const int ch0 = tid * CPT;
    const int hd  = ch0 / C;
    float acc[CPT];
#pragma unroll
    for (int j = 0; j < CPT; ++j) acc[j] = 0.f;

    for (int e0 = start; e0 < end; e0 += 64) {
        __syncthreads();
        if (tid < 64) {
            bool vld = (e0 + tid) < end;
            int s = vld ? csr_src[e0 + tid] : n;
            s_src[tid] = s;
            float4 as4 = *(const float4*)(a_s + s * GH);
            float l[GH] = {as4.x + adh[0], as4.y + adh[1], as4.z + adh[2], as4.w + adh[3]};
#pragma unroll
            for (int h = 0; h < GH; ++h) {
                float ll = l[h] > 0.f ? l[h] : 0.2f * l[h];
                s_al[h][tid] = vld ? __expf(ll - mm[h]) * inv[h] : 0.f;
            }
        }
        __syncthreads();
        int cnt = end - e0; if (cnt > 64) cnt = 64;
        int cnt4 = (cnt + 3) & ~3;
        for (int i = 0; i < cnt4; i += 4) {
            int4   ss = *(const int4*)&s_src[i];
            float4 aa = *(const float4*)&s_al[hd][i];
            if constexpr (CPT == 4) {
                uint2 v0 = ((const uint2*)(hfeat + (size_t)ss.x * HC))[tid];
                uint2 v1 = ((const uint2*)(hfeat + (size_t)ss.y * HC))[tid];
                uint2 v2 = ((const uint2*)(hfeat + (size_t)ss.z * HC))[tid];
                uint2 v3 = ((const uint2*)(hfeat + (size_t)ss.w * HC))[tid];
                acc[0] = fmaf(aa.x, h2f(v0.x & 0xffff), acc[0]);
                acc[1] = fmaf(aa.x, h2f(v0.x >> 16),    acc[1]);
                acc[2] = fmaf(aa.x, h2f(v0.y & 0xffff), acc[2]);
                acc[3] = fmaf(aa.x, h2f(v0.y >> 16),    acc[3]);
                acc[0] = fmaf(aa.y, h2f(v1.x & 0xffff), acc[0]);
                acc[1] = fmaf(aa.y, h2f(v1.x >> 16),    acc[1]);
                acc[2] = fmaf(aa.y, h2f(v1.y & 0xffff), acc[2]);
                acc[3] = fmaf(aa.y, h2f(v1.y >> 16),    acc[3]);
                acc[0] = fmaf(aa.z, h2f(v2.x & 0xffff), acc[0]);
                acc[1] = fmaf(aa.z, h2f(v2.x >> 16),    acc[1]);
                acc[2] = fmaf(aa.z, h2f(v2.y & 0xffff), acc[2]);
                acc[3] = fmaf(aa.z, h2f(v2.y >> 16),    acc[3]);
                acc[0] = fmaf(aa.w, h2f(v3.x & 0xffff), acc[0]);
                acc[1] = fmaf(aa.w, h2f(v3.x >> 16),    acc[1]);
                acc[2] = fmaf(aa.w, h2f(v3.y & 0xffff), acc[2]);
                acc[3] = fmaf(aa.w, h2f(v3.y >> 16),    acc[3]);
            } else {
                unsigned v0 = ((const unsigned*)(hfeat + (size_t)ss.x * HC))[tid];
                unsigned v1 = ((const unsigned*)(hfeat + (size_t)ss.y * HC))[tid];
                unsigned v2 = ((const unsigned*)(hfeat + (size_t)ss.z * HC))[tid];
                unsigned v3 = ((const unsigned*)(hfeat + (size_t)ss.w * HC))[tid];
                acc[0] = fmaf(aa.x, h2f(v0 & 0xffff), acc[0]);
                acc[1] = fmaf(aa.x, h2f(v0 >> 16),    acc[1]);
                acc[0] = fmaf(aa.y, h2f(v1 & 0xffff), acc[0]);
                acc[1] = fmaf(aa.y, h2f(v1 >> 16),    acc[1]);
                acc[0] = fmaf(aa.z, h2f(v2 & 0xffff), acc[0]);
                acc[1] = fmaf(aa.z, h2f(v2 >> 16),    acc[1]);
                acc[0] = fmaf(aa.w, h2f(v3 & 0xffff), acc[0]);
                acc[1] = fmaf(aa.w, h2f(v3 >> 16),    acc[1]);
            }
        }
    }

    // epilogue: bias + ELU -> fp16
    unsigned short hs[CPT];
#pragma unroll
    for (int j = 0; j < CPT; ++j) {
        float v = acc[j] + bias[ch0 + j];
        v = v > 0.f ? v : expm1f(v);
        hs[j] = f2h_bits(v);
    }
    unsigned short* op = of16 + (size_t)n * HC + ch0;
    if constexpr (CPT == 4) {
        uint2 hw = make_uint2((unsigned)hs[0] | ((unsigned)hs[1] << 16),
                              (unsigned)hs[2] | ((unsigned)hs[3] << 16));
        *(uint2*)op = hw;
    } else {
        *(unsigned*)op = (unsigned)hs[0] | ((unsigned)hs[1] << 16);
    }
}

// ---------------------------------------------------------------------------
// Final layer aggregation (r16): fp16 h input (halved gather vs fp32),
// head-mean + bias -> fp32 d_out.  C=64, HC=256, BLOCK=128, 2 ch/thread.
// ---------------------------------------------------------------------------
__global__ __launch_bounds__(128) void gat_aggregate_final_f16(
        const unsigned short* __restrict__ hfeat,
        const float* __restrict__ a_s,
        const float* __restrict__ a_d,
        const int* __restrict__ offsets,
        const int* __restrict__ csr_src,
        const float* __restrict__ bias,
        float* __restrict__ outf) {
    constexpr int C = 64, HC = GH * C;
    const int n     = blockIdx.x;
    const int tid   = threadIdx.x;
    const int start = offsets[n];
    const int end   = offsets[n + 1];

    __shared__ float s_m[GH];
    __shared__ float s_den[GH];
    __shared__ int   s_src[64];
    __shared__ float s_al[GH][68];
    __shared__ float sacc[256];

    const float4 ad4 = *(const float4*)(a_d + n * GH);
    const float adh[GH] = {ad4.x, ad4.y, ad4.z, ad4.w};

    if (tid < 64) {
        float lmax[GH], lsum[GH];
#pragma unroll
        for (int h = 0; h < GH; ++h) lmax[h] = -1e30f;
        for (int e = start + tid; e < end; e += 64) {
            int s = csr_src[e];
            float4 as4 = *(const float4*)(a_s + s * GH);
            float l[GH] = {as4.x + adh[0], as4.y + adh[1], as4.z + adh[2], as4.w + adh[3]};
#pragma unroll
            for (int h = 0; h < GH; ++h) {
                float ll = l[h] > 0.f ? l[h] : 0.2f * l[h];
                lmax[h] = fmaxf(lmax[h], ll);
            }
        }
#pragma unroll
        for (int h = 0; h < GH; ++h)
#pragma unroll
            for (int o = 32; o; o >>= 1) lmax[h] = fmaxf(lmax[h], __shfl_xor(lmax[h], o));
#pragma unroll
        for (int h = 0; h < GH; ++h) lsum[h] = 0.f;
        for (int e = start + tid; e < end; e += 64) {
            int s = csr_src[e];
            float4 as4 = *(const float4*)(a_s + s * GH);
            float l[GH] = {as4.x + adh[0], as4.y + adh[1], as4.z + adh[2], as4.w + adh[3]};
#pragma unroll
            for (int h = 0; h < GH; ++h) {
                float ll = l[h] > 0.f ? l[h] : 0.2f * l[h];
                lsum[h] += __expf(ll - lmax[h]);
            }
        }
#pragma unroll
        for (int h = 0; h < GH; ++h)
#pragma unroll
            for (int o = 32; o; o >>= 1) lsum[h] += __shfl_xor(lsum[h], o);
        if (tid == 0) {
#pragma unroll
            for (int h = 0; h < GH; ++h) { s_m[h] = lmax[h]; s_den[h] = lsum[h]; }
        }
    }
    __syncthreads();

    float mm[GH], inv[GH];
#pragma unroll
    for (int h = 0; h < GH; ++h) { mm[h] = s_m[h]; inv[h] = 1.0f / s_den[h]; }

    const int hd = (2 * tid) / C;
    float acc0 = 0.f, acc1 = 0.f;

    for (int e0 = start; e0 < end; e0 += 64) {
        __syncthreads();
        if (tid < 64) {
            bool vld = (e0 + tid) < end;
            int s = vld ? csr_src[e0 + tid] : n;
            s_src[tid] = s;
            float4 as4 = *(const float4*)(a_s + s * GH);
            float l[GH] = {as4.x + adh[0], as4.y + adh[1], as4.z + adh[2], as4.w + adh[3]};
#pragma unroll
            for (int h = 0; h < GH; ++h) {
                float ll = l[h] > 0.f ? l[h] : 0.2f * l[h];
                s_al[h][tid] = vld ? __expf(ll - mm[h]) * inv[h] : 0.f;
            }
        }
        __syncthreads();
        int cnt = end - e0; if (cnt > 64) cnt = 64;
        int cnt4 = (cnt + 3) & ~3;
        for (int i = 0; i < cnt4; i += 4) {
            int4   ss = *(const int4*)&s_src[i];
            float4 aa = *(const float4*)&s_al[hd][i];
            unsigned v0 = ((const unsigned*)(hfeat + (size_t)ss.x * HC))[tid];
            unsigned v1 = ((const unsigned*)(hfeat + (size_t)ss.y * HC))[tid];
            unsigned v2 = ((const unsigned*)(hfeat + (size_t)ss.z * HC))[tid];
            unsigned v3 = ((const unsigned*)(hfeat + (size_t)ss.w * HC))[tid];
            acc0 = fmaf(aa.x, h2f(v0 & 0xffff), acc0);
            acc1 = fmaf(aa.x, h2f(v0 >> 16),    acc1);
            acc0 = fmaf(aa.y, h2f(v1 & 0xffff), acc0);
            acc1 = fmaf(aa.y, h2f(v1 >> 16),    acc1);
            acc0 = fmaf(aa.z, h2f(v2 & 0xffff), acc0);
            acc1 = fmaf(aa.z, h2f(v2 >> 16),    acc1);
            acc0 = fmaf(aa.w, h2f(v3 & 0xffff), acc0);
            acc1 = fmaf(aa.w, h2f(v3 >> 16),    acc1);
        }
    }

    sacc[2 * tid]     = acc0;
    sacc[2 * tid + 1] = acc1;
    __syncthreads();
    if (tid < C) {
        float v = 0.f;
#pragma unroll
        for (int h = 0; h < GH; ++h) v += sacc[h * C + tid];
        outf[(size_t)n * C + tid] = v * (1.0f / GH) + bias[tid];
    }
}

// ---------------------------------------------------------------------------
extern "C" void kernel_launch(void* const* d_in, const int* in_sizes, int n_in,
                              void* d_out, int out_size, void* d_ws, size_t ws_size,
                              hipStream_t stream) {
    const float* x  = (const float*)d_in[0];
    const void*  ei = d_in[1];
    const float* W[4]  = {(const float*)d_in[2],  (const float*)d_in[6],
                          (const float*)d_in[10], (const float*)d_in[14]};
    const float* AS[4] = {(const float*)d_in[3],  (const float*)d_in[7],
                          (const float*)d_in[11], (const float*)d_in[15]};
    const float* AD[4] = {(const float*)d_in[4],  (const float*)d_in[8],
                          (const float*)d_in[12], (const float*)d_in[16]};
    const float* BI[4] = {(const float*)d_in[5],  (const float*)d_in[9],
                          (const float*)d_in[13], (const float*)d_in[17]};

    char*  w   = (char*)d_ws;
    size_t off = 0;
    auto alloc = [&](size_t b) -> char* {
        char* p = w + off;
        off += (b + 255) & ~(size_t)255;
        return p;
    };
    int*   flag    = (int*)alloc(4);
    int*   counts  = (int*)alloc((GN + 1) * sizeof(int));
    int*   offsets = (int*)alloc((GN + 1) * sizeof(int));
    int*   cursor  = (int*)alloc(GN * sizeof(int));
    int*   csr_src = (int*)alloc((size_t)GETOT * sizeof(int));
    // 4 layer-pairs of (a_s, a_d), contiguous -> one memset zeroes all
    float* attb    = (float*)alloc((size_t)8 * GN * GH * sizeof(float));   // 2.56 MB
    float* aS[4], *aD[4];
    for (int i = 0; i < 4; ++i) {
        aS[i] = attb + (size_t)(2 * i)     * GN * GH;
        aD[i] = attb + (size_t)(2 * i + 1) * GN * GH;
    }
    unsigned short* hA = (unsigned short*)alloc((size_t)NROW * 512 * 2);   // GEMM out h (fp16)
    unsigned short* hB = (unsigned short*)alloc((size_t)NROW * 512 * 2);   // agg out act (fp16)
    _Float16* wt   = (_Float16*)alloc((size_t)512 * 2016 * 2);             // 2.06 MB
    (void)in_sizes; (void)n_in; (void)out_size; (void)ws_size;

    // ---- CSR by destination (layer-invariant) + zero att accumulators ----
    detect_dtype_kernel<<<1, 64, 0, stream>>>(ei, flag);
    hipMemsetAsync(counts, 0, (GN + 1) * sizeof(int), stream);
    hipMemsetAsync(attb, 0, (size_t)8 * GN * GH * sizeof(float), stream);
    int eblocks = (GETOT + 255) / 256;
    hist_kernel<<<eblocks, 256, 0, stream>>>(ei, flag, counts);
    scan_kernel<<<1, 1024, 0, stream>>>(counts, offsets, cursor);
    scatter_kernel<<<eblocks, 256, 0, stream>>>(ei, flag, cursor, csr_src);

    const dim3 tb(32, 8);
    const int NR = (GN + 127) / 128;   // 157 row blocks

    // ---- layer 0: 2000 -> 4x128 concat, ELU (A = fp32 x direct, MODE1) ----
    convert_wt<<<dim3(2016 / 32, 512 / 32), tb, 0, stream>>>(W[0], wt, 2000, 512, 2016);
    gemm_f16<1, 128><<<NR * 4, 256, 0, stream>>>(x, 2000, 2000, wt, 2016, hA, GN, 512, 4,
                                                 AS[0], AD[0], aS[0], aD[0]);
    gat_aggregate_f16<128, 4, 128><<<GN, 128, 0, stream>>>(hA, aS[0], aD[0], offsets, csr_src,
                                                           BI[0], hB);
    // ---- layer 1: 512 -> 4x64 concat, ELU ----
    convert_wt<<<dim3(512 / 32, 256 / 32), tb, 0, stream>>>(W[1], wt, 512, 256, 512);
    gemm_f16<0, 64><<<NR * 2, 256, 0, stream>>>(hB, 512, 512, wt, 512, hA, GN, 256, 2,
                                                AS[1], AD[1], aS[1], aD[1]);
    gat_aggregate_f16<64, 4, 64><<<GN, 64, 0, stream>>>(hA, aS[1], aD[1], offsets, csr_src,
                                                        BI[1], hB);
    // ---- layer 2: 256 -> 4x32 concat, ELU ----
    convert_wt<<<dim3(256 / 32, 128 / 32), tb, 0, stream>>>(W[2], wt, 256, 128, 256);
    gemm_f16<0, 32><<<NR * 1, 256, 0, stream>>>(hB, 256, 256, wt, 256, hA, GN, 128, 1,
                                                AS[2], AD[2], aS[2], aD[2]);
    gat_aggregate_f16<32, 2, 64><<<GN, 64, 0, stream>>>(hA, aS[2], aD[2], offsets, csr_src,
                                                        BI[2], hB);
    // ---- layer 3: 128 -> 4x64 mean, no ELU (fp16 h, halved final gather) ----
    convert_wt<<<dim3(128 / 32, 256 / 32), tb, 0, stream>>>(W[3], wt, 128, 256, 128);
    gemm_f16<0, 64><<<NR * 2, 256, 0, stream>>>(hB, 128, 128, wt, 128, hA, GN, 256, 2,
                                                AS[3], AD[3], aS[3], aD[3]);
    gat_aggregate_final_f16<<<GN, 128, 0, stream>>>(hA, aS[3], aD[3], offsets, csr_src,
                                                    BI[3], (float*)d_out);
}